// Round 5
// baseline (1836.730 us; speedup 1.0000x reference)
//
#include <hip/hip_runtime.h>

// ---------------- problem constants ----------------
constexpr int Nn = 50000;
constexpr int Ee = 800000;
constexpr int EF_STR  = 136; // 68 dw ≡ 4 mod 32 → 2-way (free), 16B-aligned rows
constexpr int TL_STR  = 40;  // tail stride: 20 dw ≡ 20 mod 32 → 2-way (free)
constexpr int NIN_STR = 264; // 132 dw ≡ 4 mod 32 → 2-way
constexpr int HIN_STR = 72;  // 36 dw ≡ 4 mod 32

typedef short s8v __attribute__((ext_vector_type(8)));
typedef float f4v __attribute__((ext_vector_type(4)));

__device__ __forceinline__ ushort f2bf(float f) {      // RNE (cold paths)
    uint u = __float_as_uint(f);
    uint r = (u + 0x7FFFu + ((u >> 16) & 1u)) >> 16;
    return (ushort)r;
}
__device__ __forceinline__ float bf2f(ushort s) {
    return __uint_as_float(((uint)s) << 16);
}
__device__ __forceinline__ float silu_f(float x) {
    return x * __fdividef(1.0f, 1.0f + __expf(-x));
}
// pack two fp32 → two bf16 in one dword, truncating (1 v_perm_b32)
__device__ __forceinline__ uint pack2bf_t(float lo, float hi) {
    return __builtin_amdgcn_perm(__float_as_uint(hi), __float_as_uint(lo), 0x07060302u);
}
// pack with round-half-up (h master mirror — feeds 4 layers, keep tighter)
__device__ __forceinline__ uint pack2bf_r(float lo, float hi) {
    uint a = __float_as_uint(lo) + 0x8000u;
    uint b = __float_as_uint(hi) + 0x8000u;
    return __builtin_amdgcn_perm(b, a, 0x07060302u);
}

// ---------------- weight pre-swizzle (serves as transposed-A operand) ----------------
// dst: [L, KC, t(8), lane(64), j(8)]; element = W[l][kc*32+(lane>>4)*8+j][t*16+(lane&15)]
// With swapped operands this is exactly the A-frag of W^T: A[m=out_col][k=in_col].
__global__ void __launch_bounds__(256) k_swzg(
    const float* __restrict__ src, ushort* __restrict__ dst, int K, int KC, int total)
{
    int gid = blockIdx.x * 256 + threadIdx.x;
    if (gid >= total) return;
    int per = KC * 4096;
    int l = gid / per, r = gid % per;
    int fb = r >> 9, rem = r & 511;
    int lane = rem >> 3, jj = rem & 7;
    int kc = fb >> 3, t = fb & 7;
    int k = kc * 32 + ((lane >> 4) << 3) + jj;
    int n = t * 16 + (lane & 15);
    float v = (k < K) ? src[(size_t)l * K * 128 + (size_t)k * 128 + n] : 0.0f;
    dst[gid] = f2bf(v);
}

// ---------------- incoming-edge histogram ----------------
__global__ void __launch_bounds__(256) k_count(const int* __restrict__ eidx, int* __restrict__ ecnt)
{
    int e = blockIdx.x * 256 + threadIdx.x;
    atomicAdd(&ecnt[eidx[Ee + e]], 1);
}

// ---------------- exclusive scan over node counts (single block) ----------------
__global__ void __launch_bounds__(1024) k_scan(const int* __restrict__ ecnt, int* __restrict__ cursor)
{
    __shared__ int wsum[16];
    __shared__ int carry;
    int tid = threadIdx.x, lane = tid & 63, w = tid >> 6;
    if (tid == 0) carry = 0;
    __syncthreads();
    for (int start = 0; start < Nn; start += 1024) {
        int i = start + tid;
        int x = (i < Nn) ? ecnt[i] : 0;
        int c0 = carry;
        int s = x;
        #pragma unroll
        for (int off = 1; off < 64; off <<= 1) {
            int t = __shfl_up(s, off, 64);
            if (lane >= off) s += t;
        }
        if (lane == 63) wsum[w] = s;
        __syncthreads();
        if (w == 0) {
            int t = (lane < 16) ? wsum[lane] : 0;
            #pragma unroll
            for (int off = 1; off < 16; off <<= 1) {
                int u = __shfl_up(t, off, 64);
                if (lane >= off) t += u;
            }
            if (lane < 16) wsum[lane] = t;
        }
        __syncthreads();
        int woff = (w == 0) ? 0 : wsum[w - 1];
        if (i < Nn) cursor[i] = c0 + woff + s - x;
        int blocksum = wsum[15];
        __syncthreads();
        if (tid == 0) carry = c0 + blocksum;
        __syncthreads();
    }
}

// ---------------- scatter edges into col-sorted arrays ----------------
__global__ void __launch_bounds__(256) k_scatter(
    const int* __restrict__ eidx, const float* __restrict__ edge_attr,
    int* __restrict__ cursor,
    int* __restrict__ srow, int* __restrict__ scol, float* __restrict__ sattr)
{
    int e = blockIdx.x * 256 + threadIdx.x;
    int r = eidx[e], c = eidx[Ee + e];
    int p = atomicAdd(&cursor[c], 1);
    srow[p] = r; scol[p] = c; sattr[p] = edge_attr[e];
}

// ---------------- input embedding (transposed MFMA, K=64) + coord copy ----------------
__global__ void __launch_bounds__(512, 2) k_emb(
    const float* __restrict__ h_in, const float* __restrict__ coords,
    const ushort* __restrict__ ws_, const float* __restrict__ b,
    float* __restrict__ hbuf, ushort* __restrict__ hbf, float* __restrict__ cbuf)
{
    __shared__ alignas(16) ushort s_h[64 * HIN_STR];
    const int tid = threadIdx.x;
    const int nb = blockIdx.x * 64;
    #pragma unroll
    for (int i = 0; i < 2; i++) {
        int idx = i * 512 + tid;
        int e = idx >> 4, ch = idx & 15;
        int node = nb + e;
        float4 f = make_float4(0.f, 0.f, 0.f, 0.f);
        if (node < Nn) f = *(const float4*)(h_in + (size_t)node * 64 + ch * 4);
        ushort4 u; u.x = f2bf(f.x); u.y = f2bf(f.y); u.z = f2bf(f.z); u.w = f2bf(f.w);
        *(ushort4*)(s_h + e * HIN_STR + ch * 4) = u;
    }
    if (tid < 192) {
        int n = nb + tid / 3, d = tid % 3;
        if (n < Nn) cbuf[n * 3 + d] = coords[n * 3 + d];
    }
    __syncthreads();
    const int lane = tid & 63, wave = tid >> 6;
    const int m = lane & 15, quad = lane >> 4;
    const int ws2 = wave >> 2, wt = wave & 3;
    const int rbase = ws2 * 32;
    f4v acc[2][2];
    #pragma unroll
    for (int nt = 0; nt < 2; nt++) { acc[nt][0] = (f4v){0,0,0,0}; acc[nt][1] = (f4v){0,0,0,0}; }
    const ushort* aBase = ws_ + wt * 1024 + lane * 8;
    #pragma unroll
    for (int kc = 0; kc < 2; kc++) {
        s8v a0 = *(const s8v*)(aBase + kc * 4096);
        s8v a1 = *(const s8v*)(aBase + kc * 4096 + 512);
        #pragma unroll
        for (int nt = 0; nt < 2; nt++) {
            s8v bf = *(const s8v*)(s_h + (rbase + nt * 16 + m) * HIN_STR + kc * 32 + quad * 8);
            acc[nt][0] = __builtin_amdgcn_mfma_f32_16x16x32_bf16(a0, bf, acc[nt][0], 0, 0, 0);
            acc[nt][1] = __builtin_amdgcn_mfma_f32_16x16x32_bf16(a1, bf, acc[nt][1], 0, 0, 0);
        }
    }
    #pragma unroll
    for (int nt = 0; nt < 2; nt++) {
        int node = nb + rbase + nt * 16 + m;
        if (node < Nn) {
            #pragma unroll
            for (int ct = 0; ct < 2; ct++) {
                int colb = (wt * 2 + ct) * 16 + quad * 4;
                float4 bb = *(const float4*)(b + colb);
                float v0 = acc[nt][ct][0] + bb.x;
                float v1 = acc[nt][ct][1] + bb.y;
                float v2 = acc[nt][ct][2] + bb.z;
                float v3 = acc[nt][ct][3] + bb.w;
                *(float4*)(hbuf + (size_t)node * 128 + colb) = make_float4(v0, v1, v2, v3);
                uint2 pk; pk.x = pack2bf_r(v0, v1); pk.y = pack2bf_r(v2, v3);
                *(uint2*)(hbf + (size_t)node * 128 + colb) = pk;
            }
        }
    }
}

// ---------------- fused edge MLP + run-reduced aggregation (transposed MFMA) ----------------
// Operand swap: mfma(W_frag, act_frag) → output [col][edge] per-lane: edge=lane&15 fixed,
// 4 consecutive cols per reg group → 8B LDS/global stores. LDS = 40960 B → 4 blocks/CU.
__global__ void __launch_bounds__(512, 8) k_edge(
    const ushort* __restrict__ hbf, const float* __restrict__ cbuf,
    const int* __restrict__ srow, const int* __restrict__ scol, const float* __restrict__ sattr,
    const ushort* __restrict__ w1s, const float* __restrict__ b1,
    const ushort* __restrict__ w2s, const float* __restrict__ b2,
    const ushort* __restrict__ cw1s, const float* __restrict__ cb1,
    const float* __restrict__ cwc,
    float* __restrict__ agg_feat, float* __restrict__ agg_coord)
{
    __shared__ alignas(16) ushort s_a[64 * EF_STR];  // h[col] → efa
    __shared__ alignas(16) ushort s_b[64 * EF_STR];  // h[row] → efb
    __shared__ alignas(16) ushort s_t[64 * TL_STR];  // K-tail → coord partials (f32 s20)
    __shared__ int   s_col[64];
    __shared__ float s_cd[64 * 3];

    const int tid = threadIdx.x;
    const int eb = blockIdx.x * 64;

    if (tid < 64) {
        int rw = srow[eb + tid], cl = scol[eb + tid];
        s_col[tid] = cl;
        float d0 = cbuf[rw * 3 + 0] - cbuf[cl * 3 + 0];
        float d1 = cbuf[rw * 3 + 1] - cbuf[cl * 3 + 1];
        float d2 = cbuf[rw * 3 + 2] - cbuf[cl * 3 + 2];
        s_cd[tid * 3 + 0] = d0; s_cd[tid * 3 + 1] = d1; s_cd[tid * 3 + 2] = d2;
        float dist = d0 * d0 + d1 * d1 + d2 * d2;
        s_t[tid * TL_STR + 0] = f2bf(dist);
        s_t[tid * TL_STR + 1] = f2bf(sattr[eb + tid]);
        uint* zp = (uint*)(s_t + tid * TL_STR + 2);
        #pragma unroll
        for (int z = 0; z < 15; z++) zp[z] = 0;
    }
    #pragma unroll
    for (int i = 0; i < 4; i++) {
        int idx = i * 512 + tid;
        int e = idx >> 5, ch = idx & 31;
        int node = (ch < 16) ? scol[eb + e] : srow[eb + e];
        uint4 v = *(const uint4*)(hbf + (size_t)node * 128 + (ch & 15) * 8);
        ushort* dst = (ch < 16) ? (s_a + e * EF_STR + ch * 8)
                                : (s_b + e * EF_STR + (ch - 16) * 8);
        *(uint4*)dst = v;
    }
    __syncthreads(); // B1: staging complete

    const int lane = tid & 63, wave = tid >> 6;
    const int m = lane & 15, quad = lane >> 4;
    const int ws2 = wave >> 2, wt = wave & 3;   // ws2: edge half, wt: col pair
    const int rbase = ws2 * 32;

    // ---- GEMM1^T: [32 cols] x [288 K] x [32 edges] per wave ----
    f4v acc[2][2]; // [nt edge-tile][ct col-tile]
    #pragma unroll
    for (int nt = 0; nt < 2; nt++) { acc[nt][0] = (f4v){0,0,0,0}; acc[nt][1] = (f4v){0,0,0,0}; }
    {
        const ushort* aBase = w1s + wt * 1024 + (size_t)lane * 8;
        #pragma unroll
        for (int kc = 0; kc < 4; kc++) {      // K 0..127 from s_a (h[col])
            s8v a0 = *(const s8v*)(aBase + kc * 4096);
            s8v a1 = *(const s8v*)(aBase + kc * 4096 + 512);
            #pragma unroll
            for (int nt = 0; nt < 2; nt++) {
                s8v bf = *(const s8v*)(s_a + (rbase + nt * 16 + m) * EF_STR + kc * 32 + quad * 8);
                acc[nt][0] = __builtin_amdgcn_mfma_f32_16x16x32_bf16(a0, bf, acc[nt][0], 0, 0, 0);
                acc[nt][1] = __builtin_amdgcn_mfma_f32_16x16x32_bf16(a1, bf, acc[nt][1], 0, 0, 0);
            }
        }
        #pragma unroll
        for (int kc = 4; kc < 8; kc++) {      // K 128..255 from s_b (h[row])
            s8v a0 = *(const s8v*)(aBase + kc * 4096);
            s8v a1 = *(const s8v*)(aBase + kc * 4096 + 512);
            #pragma unroll
            for (int nt = 0; nt < 2; nt++) {
                s8v bf = *(const s8v*)(s_b + (rbase + nt * 16 + m) * EF_STR + (kc - 4) * 32 + quad * 8);
                acc[nt][0] = __builtin_amdgcn_mfma_f32_16x16x32_bf16(a0, bf, acc[nt][0], 0, 0, 0);
                acc[nt][1] = __builtin_amdgcn_mfma_f32_16x16x32_bf16(a1, bf, acc[nt][1], 0, 0, 0);
            }
        }
        {                                      // K 256..287 from s_t
            s8v a0 = *(const s8v*)(aBase + 8 * 4096);
            s8v a1 = *(const s8v*)(aBase + 8 * 4096 + 512);
            #pragma unroll
            for (int nt = 0; nt < 2; nt++) {
                s8v bf = *(const s8v*)(s_t + (rbase + nt * 16 + m) * TL_STR + quad * 8);
                acc[nt][0] = __builtin_amdgcn_mfma_f32_16x16x32_bf16(a0, bf, acc[nt][0], 0, 0, 0);
                acc[nt][1] = __builtin_amdgcn_mfma_f32_16x16x32_bf16(a1, bf, acc[nt][1], 0, 0, 0);
            }
        }
    }
    __syncthreads(); // B2: GEMM1 reads done — s_a reusable

    // epilogue1 → s_a: 4 consecutive cols per group → packed 8B writes
    #pragma unroll
    for (int nt = 0; nt < 2; nt++) {
        int edge = rbase + nt * 16 + m;
        #pragma unroll
        for (int ct = 0; ct < 2; ct++) {
            int colb = (wt * 2 + ct) * 16 + quad * 4;
            float4 bb = *(const float4*)(b1 + colb);
            float v0 = silu_f(acc[nt][ct][0] + bb.x);
            float v1 = silu_f(acc[nt][ct][1] + bb.y);
            float v2 = silu_f(acc[nt][ct][2] + bb.z);
            float v3 = silu_f(acc[nt][ct][3] + bb.w);
            uint2 pk; pk.x = pack2bf_t(v0, v1); pk.y = pack2bf_t(v2, v3);
            *(uint2*)(s_a + edge * EF_STR + colb) = pk;
        }
    }
    __syncthreads(); // B3: efa ready

    // ---- GEMM2^T: K=128 from s_a; epilogue → s_b ----
    {
        f4v acc2[2][2];
        #pragma unroll
        for (int nt = 0; nt < 2; nt++) { acc2[nt][0] = (f4v){0,0,0,0}; acc2[nt][1] = (f4v){0,0,0,0}; }
        const ushort* aBase = w2s + wt * 1024 + (size_t)lane * 8;
        #pragma unroll
        for (int kc = 0; kc < 4; kc++) {
            s8v a0 = *(const s8v*)(aBase + kc * 4096);
            s8v a1 = *(const s8v*)(aBase + kc * 4096 + 512);
            #pragma unroll
            for (int nt = 0; nt < 2; nt++) {
                s8v bf = *(const s8v*)(s_a + (rbase + nt * 16 + m) * EF_STR + kc * 32 + quad * 8);
                acc2[nt][0] = __builtin_amdgcn_mfma_f32_16x16x32_bf16(a0, bf, acc2[nt][0], 0, 0, 0);
                acc2[nt][1] = __builtin_amdgcn_mfma_f32_16x16x32_bf16(a1, bf, acc2[nt][1], 0, 0, 0);
            }
        }
        #pragma unroll
        for (int nt = 0; nt < 2; nt++) {
            int edge = rbase + nt * 16 + m;
            #pragma unroll
            for (int ct = 0; ct < 2; ct++) {
                int colb = (wt * 2 + ct) * 16 + quad * 4;
                float4 bb = *(const float4*)(b2 + colb);
                float v0 = silu_f(acc2[nt][ct][0] + bb.x);
                float v1 = silu_f(acc2[nt][ct][1] + bb.y);
                float v2 = silu_f(acc2[nt][ct][2] + bb.z);
                float v3 = silu_f(acc2[nt][ct][3] + bb.w);
                uint2 pk; pk.x = pack2bf_t(v0, v1); pk.y = pack2bf_t(v2, v3);
                *(uint2*)(s_b + edge * EF_STR + colb) = pk;
            }
        }
    }
    __syncthreads(); // B4: efb ready

    // ---- coord gate: in-lane col sums + 2 shuffles, partials → s_t (f32 stride 20) ----
    {
        f4v acc3[2][2];
        #pragma unroll
        for (int nt = 0; nt < 2; nt++) { acc3[nt][0] = (f4v){0,0,0,0}; acc3[nt][1] = (f4v){0,0,0,0}; }
        const ushort* aBase = cw1s + wt * 1024 + (size_t)lane * 8;
        #pragma unroll
        for (int kc = 0; kc < 4; kc++) {
            s8v a0 = *(const s8v*)(aBase + kc * 4096);
            s8v a1 = *(const s8v*)(aBase + kc * 4096 + 512);
            #pragma unroll
            for (int nt = 0; nt < 2; nt++) {
                s8v bf = *(const s8v*)(s_b + (rbase + nt * 16 + m) * EF_STR + kc * 32 + quad * 8);
                acc3[nt][0] = __builtin_amdgcn_mfma_f32_16x16x32_bf16(a0, bf, acc3[nt][0], 0, 0, 0);
                acc3[nt][1] = __builtin_amdgcn_mfma_f32_16x16x32_bf16(a1, bf, acc3[nt][1], 0, 0, 0);
            }
        }
        float* s_part = (float*)s_t;   // [edge][slot 0..3], stride 20 floats
        #pragma unroll
        for (int nt = 0; nt < 2; nt++) {
            float p = 0.0f;
            #pragma unroll
            for (int ct = 0; ct < 2; ct++) {
                int colb = (wt * 2 + ct) * 16 + quad * 4;
                float4 cb = *(const float4*)(cb1 + colb);
                float4 wc = *(const float4*)(cwc + colb);
                p += silu_f(acc3[nt][ct][0] + cb.x) * wc.x;
                p += silu_f(acc3[nt][ct][1] + cb.y) * wc.y;
                p += silu_f(acc3[nt][ct][2] + cb.z) * wc.z;
                p += silu_f(acc3[nt][ct][3] + cb.w) * wc.w;
            }
            p += __shfl_xor(p, 16, 64);
            p += __shfl_xor(p, 32, 64);
            if (quad == 0) s_part[(rbase + nt * 16 + m) * 20 + wt] = p;
        }
    }
    __syncthreads(); // B5: partials ready

    if (tid < 64) {
        float4 sp = *(const float4*)((const float*)s_t + tid * 20);
        float cw = sp.x + sp.y + sp.z + sp.w;
        int cn = s_col[tid];
        unsafeAtomicAdd(&agg_coord[cn * 3 + 0], s_cd[tid * 3 + 0] * cw);
        unsafeAtomicAdd(&agg_coord[cn * 3 + 1], s_cd[tid * 3 + 1] * cw);
        unsafeAtomicAdd(&agg_coord[cn * 3 + 2], s_cd[tid * 3 + 2] * cw);
    }
    // feature aggregation: wave-uniform run-length scan over sorted cols
    {
        int j = tid & 127;
        int e0 = (tid >> 7) * 16;
        float accv = 0.0f; int cur = s_col[e0];
        #pragma unroll 4
        for (int e = e0; e < e0 + 16; e++) {
            int c = s_col[e];
            if (c != cur) {
                unsafeAtomicAdd(&agg_feat[(size_t)cur * 128 + j], accv);
                accv = 0.0f; cur = c;
            }
            accv += bf2f(s_b[e * EF_STR + j]);
        }
        unsafeAtomicAdd(&agg_feat[(size_t)cur * 128 + j], accv);
    }
}

// ---------------- node update (transposed MFMA) ----------------
__global__ void __launch_bounds__(512, 6) k_node(
    float* __restrict__ hbuf, ushort* __restrict__ hbf, float* __restrict__ cbuf,
    const float* __restrict__ agg_feat, const float* __restrict__ agg_coord,
    const int* __restrict__ ecnt,
    const ushort* __restrict__ w1s, const float* __restrict__ b1,
    const ushort* __restrict__ w2s, const float* __restrict__ b2)
{
    __shared__ alignas(16) ushort s_nin[64 * NIN_STR]; // 33792 B
    __shared__ alignas(16) ushort s_t1[64 * EF_STR];   // 17408 B
    const int tid = threadIdx.x;
    const int nb = blockIdx.x * 64;

    #pragma unroll
    for (int i = 0; i < 2; i++) {
        int idx = i * 512 + tid;
        int e = idx >> 4, ch = idx & 15;
        int node = nb + e;
        uint4 v = make_uint4(0, 0, 0, 0);
        if (node < Nn) v = *(const uint4*)(hbf + (size_t)node * 128 + ch * 8);
        *(uint4*)(s_nin + e * NIN_STR + ch * 8) = v;
    }
    #pragma unroll
    for (int i = 0; i < 4; i++) {
        int idx = i * 512 + tid;
        int e = idx >> 5, ch = idx & 31;
        int node = nb + e;
        float4 f = make_float4(0.f, 0.f, 0.f, 0.f);
        if (node < Nn) f = *(const float4*)(agg_feat + (size_t)node * 128 + ch * 4);
        uint2 pk; pk.x = pack2bf_t(f.x, f.y); pk.y = pack2bf_t(f.z, f.w);
        *(uint2*)(s_nin + e * NIN_STR + 128 + ch * 4) = pk;
    }
    if (tid < 64) {
        int n = nb + tid;
        if (n < Nn) {
            float c = (float)ecnt[n]; c = (c < 1.0f) ? 1.0f : c;
            float inv = __fdividef(1.0f, c);
            cbuf[n * 3 + 0] += agg_coord[n * 3 + 0] * inv;
            cbuf[n * 3 + 1] += agg_coord[n * 3 + 1] * inv;
            cbuf[n * 3 + 2] += agg_coord[n * 3 + 2] * inv;
        }
    }
    __syncthreads();

    const int lane = tid & 63, wave = tid >> 6;
    const int m = lane & 15, quad = lane >> 4;
    const int ws2 = wave >> 2, wt = wave & 3;
    const int rbase = ws2 * 32;

    // GEMM1^T: K=256
    {
        f4v acc[2][2];
        #pragma unroll
        for (int nt = 0; nt < 2; nt++) { acc[nt][0] = (f4v){0,0,0,0}; acc[nt][1] = (f4v){0,0,0,0}; }
        const ushort* aBase = w1s + wt * 1024 + (size_t)lane * 8;
        #pragma unroll
        for (int kc = 0; kc < 8; kc++) {
            s8v a0 = *(const s8v*)(aBase + kc * 4096);
            s8v a1 = *(const s8v*)(aBase + kc * 4096 + 512);
            #pragma unroll
            for (int nt = 0; nt < 2; nt++) {
                s8v bf = *(const s8v*)(s_nin + (rbase + nt * 16 + m) * NIN_STR + kc * 32 + quad * 8);
                acc[nt][0] = __builtin_amdgcn_mfma_f32_16x16x32_bf16(a0, bf, acc[nt][0], 0, 0, 0);
                acc[nt][1] = __builtin_amdgcn_mfma_f32_16x16x32_bf16(a1, bf, acc[nt][1], 0, 0, 0);
            }
        }
        #pragma unroll
        for (int nt = 0; nt < 2; nt++) {
            int row = rbase + nt * 16 + m;
            #pragma unroll
            for (int ct = 0; ct < 2; ct++) {
                int colb = (wt * 2 + ct) * 16 + quad * 4;
                float4 bb = *(const float4*)(b1 + colb);
                float v0 = silu_f(acc[nt][ct][0] + bb.x);
                float v1 = silu_f(acc[nt][ct][1] + bb.y);
                float v2 = silu_f(acc[nt][ct][2] + bb.z);
                float v3 = silu_f(acc[nt][ct][3] + bb.w);
                uint2 pk; pk.x = pack2bf_t(v0, v1); pk.y = pack2bf_t(v2, v3);
                *(uint2*)(s_t1 + row * EF_STR + colb) = pk;
            }
        }
    }
    __syncthreads();

    // GEMM2^T: K=128, residual epilogue (vectorized)
    {
        f4v acc[2][2];
        #pragma unroll
        for (int nt = 0; nt < 2; nt++) { acc[nt][0] = (f4v){0,0,0,0}; acc[nt][1] = (f4v){0,0,0,0}; }
        const ushort* aBase = w2s + wt * 1024 + (size_t)lane * 8;
        #pragma unroll
        for (int kc = 0; kc < 4; kc++) {
            s8v a0 = *(const s8v*)(aBase + kc * 4096);
            s8v a1 = *(const s8v*)(aBase + kc * 4096 + 512);
            #pragma unroll
            for (int nt = 0; nt < 2; nt++) {
                s8v bf = *(const s8v*)(s_t1 + (rbase + nt * 16 + m) * EF_STR + kc * 32 + quad * 8);
                acc[nt][0] = __builtin_amdgcn_mfma_f32_16x16x32_bf16(a0, bf, acc[nt][0], 0, 0, 0);
                acc[nt][1] = __builtin_amdgcn_mfma_f32_16x16x32_bf16(a1, bf, acc[nt][1], 0, 0, 0);
            }
        }
        #pragma unroll
        for (int nt = 0; nt < 2; nt++) {
            int node = nb + rbase + nt * 16 + m;
            if (node < Nn) {
                #pragma unroll
                for (int ct = 0; ct < 2; ct++) {
                    int colb = (wt * 2 + ct) * 16 + quad * 4;
                    float4 bb = *(const float4*)(b2 + colb);
                    float4 old = *(const float4*)(hbuf + (size_t)node * 128 + colb);
                    float v0 = old.x + acc[nt][ct][0] + bb.x;
                    float v1 = old.y + acc[nt][ct][1] + bb.y;
                    float v2 = old.z + acc[nt][ct][2] + bb.z;
                    float v3 = old.w + acc[nt][ct][3] + bb.w;
                    *(float4*)(hbuf + (size_t)node * 128 + colb) = make_float4(v0, v1, v2, v3);
                    uint2 pk; pk.x = pack2bf_r(v0, v1); pk.y = pack2bf_r(v2, v3);
                    *(uint2*)(hbf + (size_t)node * 128 + colb) = pk;
                }
            }
        }
    }
}

// ---------------- output embedding (transposed MFMA) + coords out ----------------
__global__ void __launch_bounds__(512, 2) k_emb_out(
    const ushort* __restrict__ hbf, const float* __restrict__ cbuf,
    const ushort* __restrict__ ws_, const float* __restrict__ b, float* __restrict__ out)
{
    __shared__ alignas(16) ushort s_h[64 * EF_STR];
    const int tid = threadIdx.x;
    const int nb = blockIdx.x * 64;
    #pragma unroll
    for (int i = 0; i < 2; i++) {
        int idx = i * 512 + tid;
        int e = idx >> 4, ch = idx & 15;
        int node = nb + e;
        uint4 v = make_uint4(0, 0, 0, 0);
        if (node < Nn) v = *(const uint4*)(hbf + (size_t)node * 128 + ch * 8);
        *(uint4*)(s_h + e * EF_STR + ch * 8) = v;
    }
    if (tid < 192) {
        int n = nb + tid / 3, d = tid % 3;
        if (n < Nn) out[(size_t)Nn * 128 + n * 3 + d] = cbuf[n * 3 + d];
    }
    __syncthreads();
    const int lane = tid & 63, wave = tid >> 6;
    const int m = lane & 15, quad = lane >> 4;
    const int ws2 = wave >> 2, wt = wave & 3;
    const int rbase = ws2 * 32;
    f4v acc[2][2];
    #pragma unroll
    for (int nt = 0; nt < 2; nt++) { acc[nt][0] = (f4v){0,0,0,0}; acc[nt][1] = (f4v){0,0,0,0}; }
    const ushort* aBase = ws_ + wt * 1024 + (size_t)lane * 8;
    #pragma unroll
    for (int kc = 0; kc < 4; kc++) {
        s8v a0 = *(const s8v*)(aBase + kc * 4096);
        s8v a1 = *(const s8v*)(aBase + kc * 4096 + 512);
        #pragma unroll
        for (int nt = 0; nt < 2; nt++) {
            s8v bf = *(const s8v*)(s_h + (rbase + nt * 16 + m) * EF_STR + kc * 32 + quad * 8);
            acc[nt][0] = __builtin_amdgcn_mfma_f32_16x16x32_bf16(a0, bf, acc[nt][0], 0, 0, 0);
            acc[nt][1] = __builtin_amdgcn_mfma_f32_16x16x32_bf16(a1, bf, acc[nt][1], 0, 0, 0);
        }
    }
    #pragma unroll
    for (int nt = 0; nt < 2; nt++) {
        int node = nb + rbase + nt * 16 + m;
        if (node < Nn) {
            #pragma unroll
            for (int ct = 0; ct < 2; ct++) {
                int colb = (wt * 2 + ct) * 16 + quad * 4;
                float4 bb = *(const float4*)(b + colb);
                float4 o = make_float4(acc[nt][ct][0] + bb.x, acc[nt][ct][1] + bb.y,
                                       acc[nt][ct][2] + bb.z, acc[nt][ct][3] + bb.w);
                *(float4*)(out + (size_t)node * 128 + colb) = o;
            }
        }
    }
}

// ---------------- host launcher ----------------
extern "C" void kernel_launch(void* const* d_in, const int* in_sizes, int n_in,
                              void* d_out, int out_size, void* d_ws, size_t ws_size,
                              hipStream_t stream)
{
    const float* h_in      = (const float*)d_in[0];
    const float* coords    = (const float*)d_in[1];
    const float* edge_attr = (const float*)d_in[2];
    const float* emb_in_W  = (const float*)d_in[3];
    const float* emb_in_b  = (const float*)d_in[4];
    const float* emb_out_W = (const float*)d_in[5];
    const float* emb_out_b = (const float*)d_in[6];
    const float* eW1 = (const float*)d_in[7];
    const float* eb1 = (const float*)d_in[8];
    const float* eW2 = (const float*)d_in[9];
    const float* eb2 = (const float*)d_in[10];
    const float* cW1 = (const float*)d_in[11];
    const float* cb1 = (const float*)d_in[12];
    const float* cWc = (const float*)d_in[13];
    const float* nW1 = (const float*)d_in[14];
    const float* nb1 = (const float*)d_in[15];
    const float* nW2 = (const float*)d_in[16];
    const float* nb2 = (const float*)d_in[17];
    const int*  eidx = (const int*)d_in[18];

    size_t off = 0;
    char* base = (char*)d_ws;
    auto alloc = [&](size_t bytes) -> char* {
        char* p = base + off;
        off += (bytes + 255) & ~(size_t)255;
        return p;
    };
    float*  hbuf      = (float*)alloc((size_t)Nn * 128 * 4);
    ushort* hbf       = (ushort*)alloc((size_t)Nn * 128 * 2);
    float*  cbuf      = (float*)alloc((size_t)Nn * 3 * 4);
    int*    ecnt      = (int*)alloc((size_t)Nn * 4);
    int*    cursor    = (int*)alloc((size_t)Nn * 4);
    int*    srow      = (int*)alloc((size_t)Ee * 4);
    int*    scol      = (int*)alloc((size_t)Ee * 4);
    float*  sattr     = (float*)alloc((size_t)Ee * 4);
    float*  agg_feat  = (float*)alloc((size_t)Nn * 128 * 4);
    float*  agg_coord = (float*)alloc((size_t)Nn * 3 * 4);
    ushort* eW1s      = (ushort*)alloc((size_t)4 * 36864 * 2);
    ushort* eW2s      = (ushort*)alloc((size_t)4 * 16384 * 2);
    ushort* cW1s      = (ushort*)alloc((size_t)4 * 16384 * 2);
    ushort* nW1s      = (ushort*)alloc((size_t)4 * 32768 * 2);
    ushort* nW2s      = (ushort*)alloc((size_t)4 * 16384 * 2);
    ushort* eInWs     = (ushort*)alloc((size_t)8192 * 2);
    ushort* eOutWs    = (ushort*)alloc((size_t)16384 * 2);

    k_swzg<<<(4*9*4096+255)/256, 256, 0, stream>>>(eW1, eW1s, 258, 9, 4*9*4096);
    k_swzg<<<(4*4*4096+255)/256, 256, 0, stream>>>(eW2, eW2s, 128, 4, 4*4*4096);
    k_swzg<<<(4*4*4096+255)/256, 256, 0, stream>>>(cW1, cW1s, 128, 4, 4*4*4096);
    k_swzg<<<(4*8*4096+255)/256, 256, 0, stream>>>(nW1, nW1s, 256, 8, 4*8*4096);
    k_swzg<<<(4*4*4096+255)/256, 256, 0, stream>>>(nW2, nW2s, 128, 4, 4*4*4096);
    k_swzg<<<(2*4096+255)/256,   256, 0, stream>>>(emb_in_W,  eInWs,  64, 2, 2*4096);
    k_swzg<<<(4*4096+255)/256,   256, 0, stream>>>(emb_out_W, eOutWs, 128, 4, 4*4096);

    hipMemsetAsync(ecnt, 0, (size_t)Nn * 4, stream);
    k_count<<<Ee / 256, 256, 0, stream>>>(eidx, ecnt);
    k_scan<<<1, 1024, 0, stream>>>(ecnt, cursor);
    k_scatter<<<Ee / 256, 256, 0, stream>>>(eidx, edge_attr, cursor, srow, scol, sattr);
    k_emb<<<(Nn + 63) / 64, 512, 0, stream>>>(h_in, coords, eInWs, emb_in_b, hbuf, hbf, cbuf);

    for (int l = 0; l < 4; l++) {
        hipMemsetAsync(agg_feat, 0, (size_t)Nn * 128 * 4, stream);
        hipMemsetAsync(agg_coord, 0, (size_t)Nn * 3 * 4, stream);
        k_edge<<<Ee / 64, 512, 0, stream>>>(
            hbf, cbuf, srow, scol, sattr,
            eW1s + (size_t)l * 36864, eb1 + l * 128,
            eW2s + (size_t)l * 16384, eb2 + l * 128,
            cW1s + (size_t)l * 16384, cb1 + l * 128,
            cWc + l * 128,
            agg_feat, agg_coord);
        k_node<<<(Nn + 63) / 64, 512, 0, stream>>>(
            hbuf, hbf, cbuf, agg_feat, agg_coord, ecnt,
            nW1s + (size_t)l * 32768, nb1 + l * 128,
            nW2s + (size_t)l * 16384, nb2 + l * 128);
    }
    k_emb_out<<<(Nn + 63) / 64, 512, 0, stream>>>(hbf, cbuf, eOutWs, emb_out_b, (float*)d_out);
}

// Round 6
// 1789.442 us; speedup vs baseline: 1.0264x; 1.0264x over previous
//
#include <hip/hip_runtime.h>

// ---------------- problem constants ----------------
constexpr int Nn = 50000;
constexpr int Ee = 800000;
constexpr int EF_STR  = 136; // 68 dw ≡ 4 mod 32; reads uniform-8; writes fixed by XOR-16 col swizzle
constexpr int TL_STR  = 40;  // tail stride: 20 dw (2-way max, tiny traffic)
constexpr int NIN_STR = 264; // 132 dw ≡ 4 mod 32
constexpr int HIN_STR = 72;  // 36 dw ≡ 4 mod 32

typedef short s8v __attribute__((ext_vector_type(8)));
typedef float f4v __attribute__((ext_vector_type(4)));

__device__ __forceinline__ ushort f2bf(float f) {      // RNE (cold paths)
    uint u = __float_as_uint(f);
    uint r = (u + 0x7FFFu + ((u >> 16) & 1u)) >> 16;
    return (ushort)r;
}
__device__ __forceinline__ ushort f2bf_t(float f) {    // truncate (hot paths)
    return (ushort)(__float_as_uint(f) >> 16);
}
__device__ __forceinline__ float bf2f(ushort s) {
    return __uint_as_float(((uint)s) << 16);
}
__device__ __forceinline__ float silu_f(float x) {
    return x * __fdividef(1.0f, 1.0f + __expf(-x));
}
__device__ __forceinline__ uint pack2bf_t(float lo, float hi) {
    return __builtin_amdgcn_perm(__float_as_uint(hi), __float_as_uint(lo), 0x07060302u);
}
__device__ __forceinline__ uint pack2bf_r(float lo, float hi) {
    uint a = __float_as_uint(lo) + 0x8000u;
    uint b = __float_as_uint(hi) + 0x8000u;
    return __builtin_amdgcn_perm(b, a, 0x07060302u);
}

// ---------------- weight pre-swizzle into MFMA B-fragment order ----------------
// dst: [L, KC, t(8), lane(64), j(8)]; element = W[l][kc*32+(lane>>4)*8+j][t*16+(lane&15)]
__global__ void __launch_bounds__(256) k_swzg(
    const float* __restrict__ src, ushort* __restrict__ dst, int K, int KC, int total)
{
    int gid = blockIdx.x * 256 + threadIdx.x;
    if (gid >= total) return;
    int per = KC * 4096;
    int l = gid / per, r = gid % per;
    int fb = r >> 9, rem = r & 511;
    int lane = rem >> 3, jj = rem & 7;
    int kc = fb >> 3, t = fb & 7;
    int k = kc * 32 + ((lane >> 4) << 3) + jj;
    int n = t * 16 + (lane & 15);
    float v = (k < K) ? src[(size_t)l * K * 128 + (size_t)k * 128 + n] : 0.0f;
    dst[gid] = f2bf(v);
}

// ---------------- incoming-edge histogram ----------------
__global__ void __launch_bounds__(256) k_count(const int* __restrict__ eidx, int* __restrict__ ecnt)
{
    int e = blockIdx.x * 256 + threadIdx.x;
    atomicAdd(&ecnt[eidx[Ee + e]], 1);
}

// ---------------- exclusive scan over node counts (single block) ----------------
__global__ void __launch_bounds__(1024) k_scan(const int* __restrict__ ecnt, int* __restrict__ cursor)
{
    __shared__ int wsum[16];
    __shared__ int carry;
    int tid = threadIdx.x, lane = tid & 63, w = tid >> 6;
    if (tid == 0) carry = 0;
    __syncthreads();
    for (int start = 0; start < Nn; start += 1024) {
        int i = start + tid;
        int x = (i < Nn) ? ecnt[i] : 0;
        int c0 = carry;
        int s = x;
        #pragma unroll
        for (int off = 1; off < 64; off <<= 1) {
            int t = __shfl_up(s, off, 64);
            if (lane >= off) s += t;
        }
        if (lane == 63) wsum[w] = s;
        __syncthreads();
        if (w == 0) {
            int t = (lane < 16) ? wsum[lane] : 0;
            #pragma unroll
            for (int off = 1; off < 16; off <<= 1) {
                int u = __shfl_up(t, off, 64);
                if (lane >= off) t += u;
            }
            if (lane < 16) wsum[lane] = t;
        }
        __syncthreads();
        int woff = (w == 0) ? 0 : wsum[w - 1];
        if (i < Nn) cursor[i] = c0 + woff + s - x;
        int blocksum = wsum[15];
        __syncthreads();
        if (tid == 0) carry = c0 + blocksum;
        __syncthreads();
    }
}

// ---------------- scatter edges into col-sorted arrays ----------------
__global__ void __launch_bounds__(256) k_scatter(
    const int* __restrict__ eidx, const float* __restrict__ edge_attr,
    int* __restrict__ cursor,
    int* __restrict__ srow, int* __restrict__ scol, float* __restrict__ sattr)
{
    int e = blockIdx.x * 256 + threadIdx.x;
    int r = eidx[e], c = eidx[Ee + e];
    int p = atomicAdd(&cursor[c], 1);
    srow[p] = r; scol[p] = c; sattr[p] = edge_attr[e];
}

// ---------------- input embedding (transposed MFMA, K=64) + coord copy ----------------
__global__ void __launch_bounds__(512, 2) k_emb(
    const float* __restrict__ h_in, const float* __restrict__ coords,
    const ushort* __restrict__ ws_, const float* __restrict__ b,
    float* __restrict__ hbuf, ushort* __restrict__ hbf, float* __restrict__ cbuf)
{
    __shared__ alignas(16) ushort s_h[64 * HIN_STR];
    const int tid = threadIdx.x;
    const int nb = blockIdx.x * 64;
    #pragma unroll
    for (int i = 0; i < 2; i++) {
        int idx = i * 512 + tid;
        int e = idx >> 4, ch = idx & 15;
        int node = nb + e;
        float4 f = make_float4(0.f, 0.f, 0.f, 0.f);
        if (node < Nn) f = *(const float4*)(h_in + (size_t)node * 64 + ch * 4);
        ushort4 u; u.x = f2bf(f.x); u.y = f2bf(f.y); u.z = f2bf(f.z); u.w = f2bf(f.w);
        *(ushort4*)(s_h + e * HIN_STR + ch * 4) = u;
    }
    if (tid < 192) {
        int n = nb + tid / 3, d = tid % 3;
        if (n < Nn) cbuf[n * 3 + d] = coords[n * 3 + d];
    }
    __syncthreads();
    const int lane = tid & 63, wave = tid >> 6;
    const int m = lane & 15, quad = lane >> 4;
    const int ws2 = wave >> 2, wt = wave & 3;
    const int rbase = ws2 * 32;
    f4v acc[2][2];
    #pragma unroll
    for (int nt = 0; nt < 2; nt++) { acc[nt][0] = (f4v){0,0,0,0}; acc[nt][1] = (f4v){0,0,0,0}; }
    const ushort* aBase = ws_ + wt * 1024 + lane * 8;
    #pragma unroll
    for (int kc = 0; kc < 2; kc++) {
        s8v a0 = *(const s8v*)(aBase + kc * 4096);
        s8v a1 = *(const s8v*)(aBase + kc * 4096 + 512);
        #pragma unroll
        for (int nt = 0; nt < 2; nt++) {
            s8v bf = *(const s8v*)(s_h + (rbase + nt * 16 + m) * HIN_STR + kc * 32 + quad * 8);
            acc[nt][0] = __builtin_amdgcn_mfma_f32_16x16x32_bf16(a0, bf, acc[nt][0], 0, 0, 0);
            acc[nt][1] = __builtin_amdgcn_mfma_f32_16x16x32_bf16(a1, bf, acc[nt][1], 0, 0, 0);
        }
    }
    #pragma unroll
    for (int nt = 0; nt < 2; nt++) {
        int node = nb + rbase + nt * 16 + m;
        if (node < Nn) {
            #pragma unroll
            for (int ct = 0; ct < 2; ct++) {
                int colb = (wt * 2 + ct) * 16 + quad * 4;
                float4 bb = *(const float4*)(b + colb);
                float v0 = acc[nt][ct][0] + bb.x;
                float v1 = acc[nt][ct][1] + bb.y;
                float v2 = acc[nt][ct][2] + bb.z;
                float v3 = acc[nt][ct][3] + bb.w;
                *(float4*)(hbuf + (size_t)node * 128 + colb) = make_float4(v0, v1, v2, v3);
                uint2 pk; pk.x = pack2bf_r(v0, v1); pk.y = pack2bf_r(v2, v3);
                *(uint2*)(hbf + (size_t)node * 128 + colb) = pk;
            }
        }
    }
}

// ---------------- fused edge MLP + run-reduced aggregation ----------------
// R4 structure (act×W operand order) + XOR-16 column swizzle on the ef LDS buffers:
//   physical_col = logical_col ^ ((row & 8) ? 16 : 0)
// → epilogue b16 writes hit 32 distinct banks (was systematic 2-way q/q+2 aliasing).
// Reads use quad^((m&8)>>2); staging chunk and agg-scan apply the same involution.
__global__ void __launch_bounds__(512, 8) k_edge(
    const ushort* __restrict__ hbf, const float* __restrict__ cbuf,
    const int* __restrict__ srow, const int* __restrict__ scol, const float* __restrict__ sattr,
    const ushort* __restrict__ w1s, const float* __restrict__ b1,
    const ushort* __restrict__ w2s, const float* __restrict__ b2,
    const ushort* __restrict__ cw1s, const float* __restrict__ cb1,
    const float* __restrict__ cwc,
    float* __restrict__ agg_feat, float* __restrict__ agg_coord)
{
    __shared__ alignas(16) ushort s_a[64 * EF_STR];  // h[col] → efa (swizzled cols)
    __shared__ alignas(16) ushort s_b[64 * EF_STR];  // h[row] → efb (swizzled cols)
    __shared__ alignas(16) ushort s_t[64 * TL_STR];  // K-tail → coord partials (f32 s20)
    __shared__ int   s_col[64];
    __shared__ float s_cd[64 * 3];

    const int tid = threadIdx.x;
    const int eb = blockIdx.x * 64;

    if (tid < 64) {
        int rw = srow[eb + tid], cl = scol[eb + tid];
        s_col[tid] = cl;
        float d0 = cbuf[rw * 3 + 0] - cbuf[cl * 3 + 0];
        float d1 = cbuf[rw * 3 + 1] - cbuf[cl * 3 + 1];
        float d2 = cbuf[rw * 3 + 2] - cbuf[cl * 3 + 2];
        s_cd[tid * 3 + 0] = d0; s_cd[tid * 3 + 1] = d1; s_cd[tid * 3 + 2] = d2;
        float dist = d0 * d0 + d1 * d1 + d2 * d2;
        s_t[tid * TL_STR + 0] = f2bf(dist);
        s_t[tid * TL_STR + 1] = f2bf(sattr[eb + tid]);
        uint* zp = (uint*)(s_t + tid * TL_STR + 2);
        #pragma unroll
        for (int z = 0; z < 15; z++) zp[z] = 0;
    }
    // gather h[col]→s_a, h[row]→s_b; 16B chunk index swizzled per row
    #pragma unroll
    for (int i = 0; i < 4; i++) {
        int idx = i * 512 + tid;
        int e = idx >> 5, ch = idx & 31;
        int node = (ch < 16) ? scol[eb + e] : srow[eb + e];
        uint4 v = *(const uint4*)(hbf + (size_t)node * 128 + (ch & 15) * 8);
        int chp = (ch & 15) ^ ((e & 8) >> 2);   // ^2 when row bit3 set
        ushort* dst = (ch < 16) ? (s_a + e * EF_STR + chp * 8)
                                : (s_b + e * EF_STR + chp * 8);
        *(uint4*)dst = v;
    }
    __syncthreads(); // B1: staging complete

    const int lane = tid & 63, wave = tid >> 6;
    const int m = lane & 15, quad = lane >> 4;
    const int qx = quad ^ ((m & 8) >> 2);       // swizzled chunk for ef reads
    const int ws2 = wave >> 2, wt = wave & 3;
    const int rbase = ws2 * 32;
    const int cswz = (quad & 2) << 3;           // epilogue col XOR (row&8 ↔ quad&2)

    // ---- GEMM1: [32,288] @ [288,32] per wave ----
    f4v acc[2][2];
    #pragma unroll
    for (int mt = 0; mt < 2; mt++) { acc[mt][0] = (f4v){0,0,0,0}; acc[mt][1] = (f4v){0,0,0,0}; }
    {
        const ushort* bBase = w1s + wt * 1024 + (size_t)lane * 8;
        #pragma unroll
        for (int kc = 0; kc < 4; kc++) {      // K 0..127 from s_a (h[col])
            s8v b0 = *(const s8v*)(bBase + kc * 4096);
            s8v b1v = *(const s8v*)(bBase + kc * 4096 + 512);
            #pragma unroll
            for (int mt = 0; mt < 2; mt++) {
                s8v a = *(const s8v*)(s_a + (rbase + mt * 16 + m) * EF_STR + kc * 32 + qx * 8);
                acc[mt][0] = __builtin_amdgcn_mfma_f32_16x16x32_bf16(a, b0, acc[mt][0], 0, 0, 0);
                acc[mt][1] = __builtin_amdgcn_mfma_f32_16x16x32_bf16(a, b1v, acc[mt][1], 0, 0, 0);
            }
        }
        #pragma unroll
        for (int kc = 4; kc < 8; kc++) {      // K 128..255 from s_b (h[row])
            s8v b0 = *(const s8v*)(bBase + kc * 4096);
            s8v b1v = *(const s8v*)(bBase + kc * 4096 + 512);
            #pragma unroll
            for (int mt = 0; mt < 2; mt++) {
                s8v a = *(const s8v*)(s_b + (rbase + mt * 16 + m) * EF_STR + (kc - 4) * 32 + qx * 8);
                acc[mt][0] = __builtin_amdgcn_mfma_f32_16x16x32_bf16(a, b0, acc[mt][0], 0, 0, 0);
                acc[mt][1] = __builtin_amdgcn_mfma_f32_16x16x32_bf16(a, b1v, acc[mt][1], 0, 0, 0);
            }
        }
        {                                      // K 256..287 from s_t (unswizzled)
            s8v b0 = *(const s8v*)(bBase + 8 * 4096);
            s8v b1v = *(const s8v*)(bBase + 8 * 4096 + 512);
            #pragma unroll
            for (int mt = 0; mt < 2; mt++) {
                s8v a = *(const s8v*)(s_t + (rbase + mt * 16 + m) * TL_STR + quad * 8);
                acc[mt][0] = __builtin_amdgcn_mfma_f32_16x16x32_bf16(a, b0, acc[mt][0], 0, 0, 0);
                acc[mt][1] = __builtin_amdgcn_mfma_f32_16x16x32_bf16(a, b1v, acc[mt][1], 0, 0, 0);
            }
        }
    }
    __syncthreads(); // B2: GEMM1 reads done — s_a reusable

    // epilogue1 → s_a (swizzled col addresses, logical-col bias)
    #pragma unroll
    for (int tt = 0; tt < 2; tt++) {
        int col = (wt * 2 + tt) * 16 + m;
        int colx = col ^ cswz;
        float bias = b1[col];
        #pragma unroll
        for (int mt = 0; mt < 2; mt++)
            #pragma unroll
            for (int r = 0; r < 4; r++)
                s_a[(rbase + mt * 16 + quad * 4 + r) * EF_STR + colx] = f2bf_t(silu_f(acc[mt][tt][r] + bias));
    }
    __syncthreads(); // B3: efa ready

    // ---- GEMM2: K=128 from s_a; epilogue → s_b ----
    {
        f4v acc2[2][2];
        #pragma unroll
        for (int mt = 0; mt < 2; mt++) { acc2[mt][0] = (f4v){0,0,0,0}; acc2[mt][1] = (f4v){0,0,0,0}; }
        const ushort* bBase = w2s + wt * 1024 + (size_t)lane * 8;
        #pragma unroll
        for (int kc = 0; kc < 4; kc++) {
            s8v b0 = *(const s8v*)(bBase + kc * 4096);
            s8v b1v = *(const s8v*)(bBase + kc * 4096 + 512);
            #pragma unroll
            for (int mt = 0; mt < 2; mt++) {
                s8v a = *(const s8v*)(s_a + (rbase + mt * 16 + m) * EF_STR + kc * 32 + qx * 8);
                acc2[mt][0] = __builtin_amdgcn_mfma_f32_16x16x32_bf16(a, b0, acc2[mt][0], 0, 0, 0);
                acc2[mt][1] = __builtin_amdgcn_mfma_f32_16x16x32_bf16(a, b1v, acc2[mt][1], 0, 0, 0);
            }
        }
        #pragma unroll
        for (int tt = 0; tt < 2; tt++) {
            int col = (wt * 2 + tt) * 16 + m;
            int colx = col ^ cswz;
            float bias = b2[col];
            #pragma unroll
            for (int mt = 0; mt < 2; mt++)
                #pragma unroll
                for (int r = 0; r < 4; r++)
                    s_b[(rbase + mt * 16 + quad * 4 + r) * EF_STR + colx] = f2bf_t(silu_f(acc2[mt][tt][r] + bias));
        }
    }
    __syncthreads(); // B4: efb ready

    // ---- coord gate: partials per wave → s_t (f32 stride 20) ----
    {
        f4v acc3[2][2];
        #pragma unroll
        for (int mt = 0; mt < 2; mt++) { acc3[mt][0] = (f4v){0,0,0,0}; acc3[mt][1] = (f4v){0,0,0,0}; }
        const ushort* bBase = cw1s + wt * 1024 + (size_t)lane * 8;
        #pragma unroll
        for (int kc = 0; kc < 4; kc++) {
            s8v b0 = *(const s8v*)(bBase + kc * 4096);
            s8v b1v = *(const s8v*)(bBase + kc * 4096 + 512);
            #pragma unroll
            for (int mt = 0; mt < 2; mt++) {
                s8v a = *(const s8v*)(s_b + (rbase + mt * 16 + m) * EF_STR + kc * 32 + qx * 8);
                acc3[mt][0] = __builtin_amdgcn_mfma_f32_16x16x32_bf16(a, b0, acc3[mt][0], 0, 0, 0);
                acc3[mt][1] = __builtin_amdgcn_mfma_f32_16x16x32_bf16(a, b1v, acc3[mt][1], 0, 0, 0);
            }
        }
        int c0 = wt * 32 + m, c1 = wt * 32 + 16 + m;
        float bias0 = cb1[c0], wc0 = cwc[c0];
        float bias1 = cb1[c1], wc1 = cwc[c1];
        float* s_part = (float*)s_t;   // [edge][slot 0..15], stride 20 floats
        #pragma unroll
        for (int mt = 0; mt < 2; mt++)
            #pragma unroll
            for (int r = 0; r < 4; r++) {
                float p = silu_f(acc3[mt][0][r] + bias0) * wc0 + silu_f(acc3[mt][1][r] + bias1) * wc1;
                p += __shfl_xor(p, 1, 64);
                p += __shfl_xor(p, 2, 64);
                if ((m & 3) == 0) {
                    int slot = wt * 4 + (m >> 2);
                    s_part[(rbase + mt * 16 + quad * 4 + r) * 20 + slot] = p;
                }
            }
    }
    __syncthreads(); // B5: partials ready

    if (tid < 64) {
        float* s_part = (float*)s_t;
        float cw = 0.0f;
        #pragma unroll
        for (int l = 0; l < 16; l++) cw += s_part[tid * 20 + l];
        int cn = s_col[tid];
        unsafeAtomicAdd(&agg_coord[cn * 3 + 0], s_cd[tid * 3 + 0] * cw);
        unsafeAtomicAdd(&agg_coord[cn * 3 + 1], s_cd[tid * 3 + 1] * cw);
        unsafeAtomicAdd(&agg_coord[cn * 3 + 2], s_cd[tid * 3 + 2] * cw);
    }
    // feature aggregation: wave-uniform run-length scan over sorted cols (unswizzle reads)
    {
        int j = tid & 127;
        int e0 = (tid >> 7) * 16;
        float accv = 0.0f; int cur = s_col[e0];
        #pragma unroll 4
        for (int e = e0; e < e0 + 16; e++) {
            int c = s_col[e];
            if (c != cur) {
                unsafeAtomicAdd(&agg_feat[(size_t)cur * 128 + j], accv);
                accv = 0.0f; cur = c;
            }
            int jp = j ^ ((e & 8) << 1);
            accv += bf2f(s_b[e * EF_STR + jp]);
        }
        unsafeAtomicAdd(&agg_feat[(size_t)cur * 128 + j], accv);
    }
}

// ---------------- node update (transposed MFMA) ----------------
__global__ void __launch_bounds__(512, 6) k_node(
    float* __restrict__ hbuf, ushort* __restrict__ hbf, float* __restrict__ cbuf,
    const float* __restrict__ agg_feat, const float* __restrict__ agg_coord,
    const int* __restrict__ ecnt,
    const ushort* __restrict__ w1s, const float* __restrict__ b1,
    const ushort* __restrict__ w2s, const float* __restrict__ b2)
{
    __shared__ alignas(16) ushort s_nin[64 * NIN_STR]; // 33792 B
    __shared__ alignas(16) ushort s_t1[64 * EF_STR];   // 17408 B
    const int tid = threadIdx.x;
    const int nb = blockIdx.x * 64;

    #pragma unroll
    for (int i = 0; i < 2; i++) {
        int idx = i * 512 + tid;
        int e = idx >> 4, ch = idx & 15;
        int node = nb + e;
        uint4 v = make_uint4(0, 0, 0, 0);
        if (node < Nn) v = *(const uint4*)(hbf + (size_t)node * 128 + ch * 8);
        *(uint4*)(s_nin + e * NIN_STR + ch * 8) = v;
    }
    #pragma unroll
    for (int i = 0; i < 4; i++) {
        int idx = i * 512 + tid;
        int e = idx >> 5, ch = idx & 31;
        int node = nb + e;
        float4 f = make_float4(0.f, 0.f, 0.f, 0.f);
        if (node < Nn) f = *(const float4*)(agg_feat + (size_t)node * 128 + ch * 4);
        uint2 pk; pk.x = pack2bf_t(f.x, f.y); pk.y = pack2bf_t(f.z, f.w);
        *(uint2*)(s_nin + e * NIN_STR + 128 + ch * 4) = pk;
    }
    if (tid < 64) {
        int n = nb + tid;
        if (n < Nn) {
            float c = (float)ecnt[n]; c = (c < 1.0f) ? 1.0f : c;
            float inv = __fdividef(1.0f, c);
            cbuf[n * 3 + 0] += agg_coord[n * 3 + 0] * inv;
            cbuf[n * 3 + 1] += agg_coord[n * 3 + 1] * inv;
            cbuf[n * 3 + 2] += agg_coord[n * 3 + 2] * inv;
        }
    }
    __syncthreads();

    const int lane = tid & 63, wave = tid >> 6;
    const int m = lane & 15, quad = lane >> 4;
    const int ws2 = wave >> 2, wt = wave & 3;
    const int rbase = ws2 * 32;

    // GEMM1^T: K=256
    {
        f4v acc[2][2];
        #pragma unroll
        for (int nt = 0; nt < 2; nt++) { acc[nt][0] = (f4v){0,0,0,0}; acc[nt][1] = (f4v){0,0,0,0}; }
        const ushort* aBase = w1s + wt * 1024 + (size_t)lane * 8;
        #pragma unroll
        for (int kc = 0; kc < 8; kc++) {
            s8v a0 = *(const s8v*)(aBase + kc * 4096);
            s8v a1 = *(const s8v*)(aBase + kc * 4096 + 512);
            #pragma unroll
            for (int nt = 0; nt < 2; nt++) {
                s8v bf = *(const s8v*)(s_nin + (rbase + nt * 16 + m) * NIN_STR + kc * 32 + quad * 8);
                acc[nt][0] = __builtin_amdgcn_mfma_f32_16x16x32_bf16(a0, bf, acc[nt][0], 0, 0, 0);
                acc[nt][1] = __builtin_amdgcn_mfma_f32_16x16x32_bf16(a1, bf, acc[nt][1], 0, 0, 0);
            }
        }
        #pragma unroll
        for (int nt = 0; nt < 2; nt++) {
            int row = rbase + nt * 16 + m;
            #pragma unroll
            for (int ct = 0; ct < 2; ct++) {
                int colb = (wt * 2 + ct) * 16 + quad * 4;
                float4 bb = *(const float4*)(b1 + colb);
                float v0 = silu_f(acc[nt][ct][0] + bb.x);
                float v1 = silu_f(acc[nt][ct][1] + bb.y);
                float v2 = silu_f(acc[nt][ct][2] + bb.z);
                float v3 = silu_f(acc[nt][ct][3] + bb.w);
                uint2 pk; pk.x = pack2bf_t(v0, v1); pk.y = pack2bf_t(v2, v3);
                *(uint2*)(s_t1 + row * EF_STR + colb) = pk;
            }
        }
    }
    __syncthreads();

    // GEMM2^T: K=128, residual epilogue (vectorized)
    {
        f4v acc[2][2];
        #pragma unroll
        for (int nt = 0; nt < 2; nt++) { acc[nt][0] = (f4v){0,0,0,0}; acc[nt][1] = (f4v){0,0,0,0}; }
        const ushort* aBase = w2s + wt * 1024 + (size_t)lane * 8;
        #pragma unroll
        for (int kc = 0; kc < 4; kc++) {
            s8v a0 = *(const s8v*)(aBase + kc * 4096);
            s8v a1 = *(const s8v*)(aBase + kc * 4096 + 512);
            #pragma unroll
            for (int nt = 0; nt < 2; nt++) {
                s8v bf = *(const s8v*)(s_t1 + (rbase + nt * 16 + m) * EF_STR + kc * 32 + quad * 8);
                acc[nt][0] = __builtin_amdgcn_mfma_f32_16x16x32_bf16(a0, bf, acc[nt][0], 0, 0, 0);
                acc[nt][1] = __builtin_amdgcn_mfma_f32_16x16x32_bf16(a1, bf, acc[nt][1], 0, 0, 0);
            }
        }
        #pragma unroll
        for (int nt = 0; nt < 2; nt++) {
            int node = nb + rbase + nt * 16 + m;
            if (node < Nn) {
                #pragma unroll
                for (int ct = 0; ct < 2; ct++) {
                    int colb = (wt * 2 + ct) * 16 + quad * 4;
                    float4 bb = *(const float4*)(b2 + colb);
                    float4 old = *(const float4*)(hbuf + (size_t)node * 128 + colb);
                    float v0 = old.x + acc[nt][ct][0] + bb.x;
                    float v1 = old.y + acc[nt][ct][1] + bb.y;
                    float v2 = old.z + acc[nt][ct][2] + bb.z;
                    float v3 = old.w + acc[nt][ct][3] + bb.w;
                    *(float4*)(hbuf + (size_t)node * 128 + colb) = make_float4(v0, v1, v2, v3);
                    uint2 pk; pk.x = pack2bf_r(v0, v1); pk.y = pack2bf_r(v2, v3);
                    *(uint2*)(hbf + (size_t)node * 128 + colb) = pk;
                }
            }
        }
    }
}

// ---------------- output embedding (transposed MFMA) + coords out ----------------
__global__ void __launch_bounds__(512, 2) k_emb_out(
    const ushort* __restrict__ hbf, const float* __restrict__ cbuf,
    const ushort* __restrict__ ws_, const float* __restrict__ b, float* __restrict__ out)
{
    __shared__ alignas(16) ushort s_h[64 * EF_STR];
    const int tid = threadIdx.x;
    const int nb = blockIdx.x * 64;
    #pragma unroll
    for (int i = 0; i < 2; i++) {
        int idx = i * 512 + tid;
        int e = idx >> 4, ch = idx & 15;
        int node = nb + e;
        uint4 v = make_uint4(0, 0, 0, 0);
        if (node < Nn) v = *(const uint4*)(hbf + (size_t)node * 128 + ch * 8);
        *(uint4*)(s_h + e * EF_STR + ch * 8) = v;
    }
    if (tid < 192) {
        int n = nb + tid / 3, d = tid % 3;
        if (n < Nn) out[(size_t)Nn * 128 + n * 3 + d] = cbuf[n * 3 + d];
    }
    __syncthreads();
    const int lane = tid & 63, wave = tid >> 6;
    const int m = lane & 15, quad = lane >> 4;
    const int ws2 = wave >> 2, wt = wave & 3;
    const int rbase = ws2 * 32;
    f4v acc[2][2];
    #pragma unroll
    for (int nt = 0; nt < 2; nt++) { acc[nt][0] = (f4v){0,0,0,0}; acc[nt][1] = (f4v){0,0,0,0}; }
    const ushort* aBase = ws_ + wt * 1024 + (size_t)lane * 8;
    #pragma unroll
    for (int kc = 0; kc < 4; kc++) {
        s8v a0 = *(const s8v*)(aBase + kc * 4096);
        s8v a1 = *(const s8v*)(aBase + kc * 4096 + 512);
        #pragma unroll
        for (int nt = 0; nt < 2; nt++) {
            s8v bf = *(const s8v*)(s_h + (rbase + nt * 16 + m) * EF_STR + kc * 32 + quad * 8);
            acc[nt][0] = __builtin_amdgcn_mfma_f32_16x16x32_bf16(a0, bf, acc[nt][0], 0, 0, 0);
            acc[nt][1] = __builtin_amdgcn_mfma_f32_16x16x32_bf16(a1, bf, acc[nt][1], 0, 0, 0);
        }
    }
    #pragma unroll
    for (int nt = 0; nt < 2; nt++) {
        int node = nb + rbase + nt * 16 + m;
        if (node < Nn) {
            #pragma unroll
            for (int ct = 0; ct < 2; ct++) {
                int colb = (wt * 2 + ct) * 16 + quad * 4;
                float4 bb = *(const float4*)(b + colb);
                float4 o = make_float4(acc[nt][ct][0] + bb.x, acc[nt][ct][1] + bb.y,
                                       acc[nt][ct][2] + bb.z, acc[nt][ct][3] + bb.w);
                *(float4*)(out + (size_t)node * 128 + colb) = o;
            }
        }
    }
}

// ---------------- host launcher ----------------
extern "C" void kernel_launch(void* const* d_in, const int* in_sizes, int n_in,
                              void* d_out, int out_size, void* d_ws, size_t ws_size,
                              hipStream_t stream)
{
    const float* h_in      = (const float*)d_in[0];
    const float* coords    = (const float*)d_in[1];
    const float* edge_attr = (const float*)d_in[2];
    const float* emb_in_W  = (const float*)d_in[3];
    const float* emb_in_b  = (const float*)d_in[4];
    const float* emb_out_W = (const float*)d_in[5];
    const float* emb_out_b = (const float*)d_in[6];
    const float* eW1 = (const float*)d_in[7];
    const float* eb1 = (const float*)d_in[8];
    const float* eW2 = (const float*)d_in[9];
    const float* eb2 = (const float*)d_in[10];
    const float* cW1 = (const float*)d_in[11];
    const float* cb1 = (const float*)d_in[12];
    const float* cWc = (const float*)d_in[13];
    const float* nW1 = (const float*)d_in[14];
    const float* nb1 = (const float*)d_in[15];
    const float* nW2 = (const float*)d_in[16];
    const float* nb2 = (const float*)d_in[17];
    const int*  eidx = (const int*)d_in[18];

    size_t off = 0;
    char* base = (char*)d_ws;
    auto alloc = [&](size_t bytes) -> char* {
        char* p = base + off;
        off += (bytes + 255) & ~(size_t)255;
        return p;
    };
    float*  hbuf      = (float*)alloc((size_t)Nn * 128 * 4);
    ushort* hbf       = (ushort*)alloc((size_t)Nn * 128 * 2);
    float*  cbuf      = (float*)alloc((size_t)Nn * 3 * 4);
    int*    ecnt      = (int*)alloc((size_t)Nn * 4);
    int*    cursor    = (int*)alloc((size_t)Nn * 4);
    int*    srow      = (int*)alloc((size_t)Ee * 4);
    int*    scol      = (int*)alloc((size_t)Ee * 4);
    float*  sattr     = (float*)alloc((size_t)Ee * 4);
    float*  agg_feat  = (float*)alloc((size_t)Nn * 128 * 4);
    float*  agg_coord = (float*)alloc((size_t)Nn * 3 * 4);
    ushort* eW1s      = (ushort*)alloc((size_t)4 * 36864 * 2);
    ushort* eW2s      = (ushort*)alloc((size_t)4 * 16384 * 2);
    ushort* cW1s      = (ushort*)alloc((size_t)4 * 16384 * 2);
    ushort* nW1s      = (ushort*)alloc((size_t)4 * 32768 * 2);
    ushort* nW2s      = (ushort*)alloc((size_t)4 * 16384 * 2);
    ushort* eInWs     = (ushort*)alloc((size_t)8192 * 2);
    ushort* eOutWs    = (ushort*)alloc((size_t)16384 * 2);

    k_swzg<<<(4*9*4096+255)/256, 256, 0, stream>>>(eW1, eW1s, 258, 9, 4*9*4096);
    k_swzg<<<(4*4*4096+255)/256, 256, 0, stream>>>(eW2, eW2s, 128, 4, 4*4*4096);
    k_swzg<<<(4*4*4096+255)/256, 256, 0, stream>>>(cW1, cW1s, 128, 4, 4*4*4096);
    k_swzg<<<(4*8*4096+255)/256, 256, 0, stream>>>(nW1, nW1s, 256, 8, 4*8*4096);
    k_swzg<<<(4*4*4096+255)/256, 256, 0, stream>>>(nW2, nW2s, 128, 4, 4*4*4096);
    k_swzg<<<(2*4096+255)/256,   256, 0, stream>>>(emb_in_W,  eInWs,  64, 2, 2*4096);
    k_swzg<<<(4*4096+255)/256,   256, 0, stream>>>(emb_out_W, eOutWs, 128, 4, 4*4096);

    hipMemsetAsync(ecnt, 0, (size_t)Nn * 4, stream);
    k_count<<<Ee / 256, 256, 0, stream>>>(eidx, ecnt);
    k_scan<<<1, 1024, 0, stream>>>(ecnt, cursor);
    k_scatter<<<Ee / 256, 256, 0, stream>>>(eidx, edge_attr, cursor, srow, scol, sattr);
    k_emb<<<(Nn + 63) / 64, 512, 0, stream>>>(h_in, coords, eInWs, emb_in_b, hbuf, hbf, cbuf);

    for (int l = 0; l < 4; l++) {
        hipMemsetAsync(agg_feat, 0, (size_t)Nn * 128 * 4, stream);
        hipMemsetAsync(agg_coord, 0, (size_t)Nn * 3 * 4, stream);
        k_edge<<<Ee / 64, 512, 0, stream>>>(
            hbf, cbuf, srow, scol, sattr,
            eW1s + (size_t)l * 36864, eb1 + l * 128,
            eW2s + (size_t)l * 16384, eb2 + l * 128,
            cW1s + (size_t)l * 16384, cb1 + l * 128,
            cWc + l * 128,
            agg_feat, agg_coord);
        k_node<<<(Nn + 63) / 64, 512, 0, stream>>>(
            hbuf, hbf, cbuf, agg_feat, agg_coord, ecnt,
            nW1s + (size_t)l * 32768, nb1 + l * 128,
            nW2s + (size_t)l * 16384, nb2 + l * 128);
    }
    k_emb_out<<<(Nn + 63) / 64, 512, 0, stream>>>(hbf, cbuf, eOutWs, emb_out_b, (float*)d_out);
}

// Round 7
// 1676.476 us; speedup vs baseline: 1.0956x; 1.0674x over previous
//
#include <hip/hip_runtime.h>

// ---------------- problem constants ----------------
constexpr int Nn = 50000;
constexpr int Ee = 800000;
constexpr int EF_STR  = 136; // 68 dw ≡ 4 mod 32
constexpr int TL_STR  = 40;  // tail stride: 20 dw
constexpr int NIN_STR = 264; // 132 dw
constexpr int HIN_STR = 72;  // 36 dw
constexpr int NB_SCAN = (Nn + 255) / 256; // 196

typedef short s8v __attribute__((ext_vector_type(8)));
typedef float f4v __attribute__((ext_vector_type(4)));

__device__ __forceinline__ ushort f2bf(float f) {      // RNE (cold paths)
    uint u = __float_as_uint(f);
    uint r = (u + 0x7FFFu + ((u >> 16) & 1u)) >> 16;
    return (ushort)r;
}
__device__ __forceinline__ ushort f2bf_t(float f) {    // truncate (hot paths)
    return (ushort)(__float_as_uint(f) >> 16);
}
__device__ __forceinline__ float bf2f(ushort s) {
    return __uint_as_float(((uint)s) << 16);
}
__device__ __forceinline__ float silu_f(float x) {
    return x * __fdividef(1.0f, 1.0f + __expf(-x));
}
__device__ __forceinline__ uint pack2bf_t(float lo, float hi) {
    return __builtin_amdgcn_perm(__float_as_uint(hi), __float_as_uint(lo), 0x07060302u);
}
__device__ __forceinline__ uint pack2bf_r(float lo, float hi) {
    uint a = __float_as_uint(lo) + 0x8000u;
    uint b = __float_as_uint(hi) + 0x8000u;
    return __builtin_amdgcn_perm(b, a, 0x07060302u);
}

// ---------------- merged weight pre-swizzle (all 7 weight sets, one launch) ----------------
// per set: dst [L, KC, t(8), lane(64), j(8)]; element = W[l][kc*32+(lane>>4)*8+j][t*16+(lane&15)]
__device__ __forceinline__ void swz_one(const float* src, ushort* dst, int K, int KC, int idx)
{
    int per = KC * 4096;
    int l = idx / per, r = idx % per;
    int fb = r >> 9, rem = r & 511;
    int lane = rem >> 3, jj = rem & 7;
    int kc = fb >> 3, t = fb & 7;
    int k = kc * 32 + ((lane >> 4) << 3) + jj;
    int n = t * 16 + (lane & 15);
    float v = (k < K) ? src[(size_t)l * K * 128 + (size_t)k * 128 + n] : 0.0f;
    dst[idx] = f2bf(v);
}
__global__ void __launch_bounds__(256) k_swz_all(
    const float* __restrict__ eW1, const float* __restrict__ eW2, const float* __restrict__ cW1,
    const float* __restrict__ nW1, const float* __restrict__ nW2,
    const float* __restrict__ inW, const float* __restrict__ outW,
    ushort* __restrict__ o1, ushort* __restrict__ o2, ushort* __restrict__ o3,
    ushort* __restrict__ o4, ushort* __restrict__ o5,
    ushort* __restrict__ o6, ushort* __restrict__ o7)
{
    int gid = blockIdx.x * 256 + threadIdx.x;
    if (gid < 147456)      swz_one(eW1, o1, 258, 9, gid);
    else if (gid < 212992) swz_one(eW2, o2, 128, 4, gid - 147456);
    else if (gid < 278528) swz_one(cW1, o3, 128, 4, gid - 212992);
    else if (gid < 409600) swz_one(nW1, o4, 256, 8, gid - 278528);
    else if (gid < 475136) swz_one(nW2, o5, 128, 4, gid - 409600);
    else if (gid < 483328) swz_one(inW, o6, 64, 2, gid - 475136);
    else if (gid < 499712) swz_one(outW, o7, 128, 4, gid - 483328);
}

// ---------------- incoming-edge histogram ----------------
__global__ void __launch_bounds__(256) k_count(const int* __restrict__ eidx, int* __restrict__ ecnt)
{
    int e = blockIdx.x * 256 + threadIdx.x;
    atomicAdd(&ecnt[eidx[Ee + e]], 1);
}

// ---------------- multi-block exclusive scan (3 passes) ----------------
__global__ void __launch_bounds__(256) k_bsum(const int* __restrict__ ecnt, int* __restrict__ bsum)
{
    __shared__ int ws[4];
    int tid = threadIdx.x, lane = tid & 63, w = tid >> 6;
    int i = blockIdx.x * 256 + tid;
    int x = (i < Nn) ? ecnt[i] : 0;
    #pragma unroll
    for (int off = 1; off < 64; off <<= 1) x += __shfl_xor(x, off, 64);
    if (lane == 0) ws[w] = x;
    __syncthreads();
    if (tid == 0) bsum[blockIdx.x] = ws[0] + ws[1] + ws[2] + ws[3];
}
__global__ void __launch_bounds__(256) k_bscan(int* __restrict__ bsum)
{
    __shared__ int ws[4];
    int tid = threadIdx.x, lane = tid & 63, w = tid >> 6;
    int x = (tid < NB_SCAN) ? bsum[tid] : 0;
    int s = x;
    #pragma unroll
    for (int off = 1; off < 64; off <<= 1) {
        int t = __shfl_up(s, off, 64);
        if (lane >= off) s += t;
    }
    if (lane == 63) ws[w] = s;
    __syncthreads();
    if (tid == 0) { int a = 0; for (int k = 0; k < 4; k++) { int t = ws[k]; ws[k] = a; a += t; } }
    __syncthreads();
    int excl = ws[w] + s - x;
    if (tid < NB_SCAN) bsum[tid] = excl;   // in-place: bsum becomes block offsets
}
__global__ void __launch_bounds__(256) k_cursor(const int* __restrict__ ecnt,
                                               const int* __restrict__ boff, int* __restrict__ cursor)
{
    __shared__ int ws[4];
    int tid = threadIdx.x, lane = tid & 63, w = tid >> 6;
    int i = blockIdx.x * 256 + tid;
    int x = (i < Nn) ? ecnt[i] : 0;
    int s = x;
    #pragma unroll
    for (int off = 1; off < 64; off <<= 1) {
        int t = __shfl_up(s, off, 64);
        if (lane >= off) s += t;
    }
    if (lane == 63) ws[w] = s;
    __syncthreads();
    if (tid == 0) { int a = 0; for (int k = 0; k < 4; k++) { int t = ws[k]; ws[k] = a; a += t; } }
    __syncthreads();
    int excl = ws[w] + s - x + boff[blockIdx.x];
    if (i < Nn) cursor[i] = excl;
}

// ---------------- scatter edges into col-sorted arrays ----------------
__global__ void __launch_bounds__(256) k_scatter(
    const int* __restrict__ eidx, const float* __restrict__ edge_attr,
    int* __restrict__ cursor,
    int* __restrict__ srow, int* __restrict__ scol, float* __restrict__ sattr)
{
    int e = blockIdx.x * 256 + threadIdx.x;
    int r = eidx[e], c = eidx[Ee + e];
    int p = atomicAdd(&cursor[c], 1);
    srow[p] = r; scol[p] = c; sattr[p] = edge_attr[e];
}

// ---------------- input embedding (transposed MFMA, K=64) + coord copy ----------------
__global__ void __launch_bounds__(512, 2) k_emb(
    const float* __restrict__ h_in, const float* __restrict__ coords,
    const ushort* __restrict__ ws_, const float* __restrict__ b,
    float* __restrict__ hbuf, ushort* __restrict__ hbf, float* __restrict__ cbuf)
{
    __shared__ alignas(16) ushort s_h[64 * HIN_STR];
    const int tid = threadIdx.x;
    const int nb = blockIdx.x * 64;
    #pragma unroll
    for (int i = 0; i < 2; i++) {
        int idx = i * 512 + tid;
        int e = idx >> 4, ch = idx & 15;
        int node = nb + e;
        float4 f = make_float4(0.f, 0.f, 0.f, 0.f);
        if (node < Nn) f = *(const float4*)(h_in + (size_t)node * 64 + ch * 4);
        ushort4 u; u.x = f2bf(f.x); u.y = f2bf(f.y); u.z = f2bf(f.z); u.w = f2bf(f.w);
        *(ushort4*)(s_h + e * HIN_STR + ch * 4) = u;
    }
    if (tid < 192) {
        int n = nb + tid / 3, d = tid % 3;
        if (n < Nn) cbuf[n * 3 + d] = coords[n * 3 + d];
    }
    __syncthreads();
    const int lane = tid & 63, wave = tid >> 6;
    const int m = lane & 15, quad = lane >> 4;
    const int ws2 = wave >> 2, wt = wave & 3;
    const int rbase = ws2 * 32;
    f4v acc[2][2];
    #pragma unroll
    for (int nt = 0; nt < 2; nt++) { acc[nt][0] = (f4v){0,0,0,0}; acc[nt][1] = (f4v){0,0,0,0}; }
    const ushort* aBase = ws_ + wt * 1024 + lane * 8;
    #pragma unroll
    for (int kc = 0; kc < 2; kc++) {
        s8v a0 = *(const s8v*)(aBase + kc * 4096);
        s8v a1 = *(const s8v*)(aBase + kc * 4096 + 512);
        #pragma unroll
        for (int nt = 0; nt < 2; nt++) {
            s8v bf = *(const s8v*)(s_h + (rbase + nt * 16 + m) * HIN_STR + kc * 32 + quad * 8);
            acc[nt][0] = __builtin_amdgcn_mfma_f32_16x16x32_bf16(a0, bf, acc[nt][0], 0, 0, 0);
            acc[nt][1] = __builtin_amdgcn_mfma_f32_16x16x32_bf16(a1, bf, acc[nt][1], 0, 0, 0);
        }
    }
    #pragma unroll
    for (int nt = 0; nt < 2; nt++) {
        int node = nb + rbase + nt * 16 + m;
        if (node < Nn) {
            #pragma unroll
            for (int ct = 0; ct < 2; ct++) {
                int colb = (wt * 2 + ct) * 16 + quad * 4;
                float4 bb = *(const float4*)(b + colb);
                float v0 = acc[nt][ct][0] + bb.x;
                float v1 = acc[nt][ct][1] + bb.y;
                float v2 = acc[nt][ct][2] + bb.z;
                float v3 = acc[nt][ct][3] + bb.w;
                *(float4*)(hbuf + (size_t)node * 128 + colb) = make_float4(v0, v1, v2, v3);
                uint2 pk; pk.x = pack2bf_r(v0, v1); pk.y = pack2bf_r(v2, v3);
                *(uint2*)(hbf + (size_t)node * 128 + colb) = pk;
            }
        }
    }
}

// ---------------- fused edge MLP + run-reduced aggregation (R4 structure) ----------------
// bias pre-loaded into MFMA accumulators; 2×32-edge aggregation segments (halves run-atomics)
__global__ void __launch_bounds__(512, 8) k_edge(
    const ushort* __restrict__ hbf, const float* __restrict__ cbuf,
    const int* __restrict__ srow, const int* __restrict__ scol, const float* __restrict__ sattr,
    const ushort* __restrict__ w1s, const float* __restrict__ b1,
    const ushort* __restrict__ w2s, const float* __restrict__ b2,
    const ushort* __restrict__ cw1s, const float* __restrict__ cb1,
    const float* __restrict__ cwc,
    float* __restrict__ agg_feat, float* __restrict__ agg_coord)
{
    __shared__ alignas(16) ushort s_a[64 * EF_STR];  // h[col] → efa
    __shared__ alignas(16) ushort s_b[64 * EF_STR];  // h[row] → efb
    __shared__ alignas(16) ushort s_t[64 * TL_STR];  // K-tail → coord partials (f32 s20)
    __shared__ int   s_col[64];
    __shared__ float s_cd[64 * 3];

    const int tid = threadIdx.x;
    const int eb = blockIdx.x * 64;

    if (tid < 64) {
        int rw = srow[eb + tid], cl = scol[eb + tid];
        s_col[tid] = cl;
        float d0 = cbuf[rw * 3 + 0] - cbuf[cl * 3 + 0];
        float d1 = cbuf[rw * 3 + 1] - cbuf[cl * 3 + 1];
        float d2 = cbuf[rw * 3 + 2] - cbuf[cl * 3 + 2];
        s_cd[tid * 3 + 0] = d0; s_cd[tid * 3 + 1] = d1; s_cd[tid * 3 + 2] = d2;
        float dist = d0 * d0 + d1 * d1 + d2 * d2;
        s_t[tid * TL_STR + 0] = f2bf(dist);
        s_t[tid * TL_STR + 1] = f2bf(sattr[eb + tid]);
        uint* zp = (uint*)(s_t + tid * TL_STR + 2);
        #pragma unroll
        for (int z = 0; z < 15; z++) zp[z] = 0;
    }
    #pragma unroll
    for (int i = 0; i < 4; i++) {
        int idx = i * 512 + tid;
        int e = idx >> 5, ch = idx & 31;
        int node = (ch < 16) ? scol[eb + e] : srow[eb + e];
        uint4 v = *(const uint4*)(hbf + (size_t)node * 128 + (ch & 15) * 8);
        ushort* dst = (ch < 16) ? (s_a + e * EF_STR + ch * 8)
                                : (s_b + e * EF_STR + (ch - 16) * 8);
        *(uint4*)dst = v;
    }
    __syncthreads(); // B1: staging complete

    const int lane = tid & 63, wave = tid >> 6;
    const int m = lane & 15, quad = lane >> 4;
    const int ws2 = wave >> 2, wt = wave & 3;
    const int rbase = ws2 * 32;

    // ---- GEMM1: [32,288] @ [288,32] per wave (bias pre-loaded into acc) ----
    f4v acc[2][2];
    {
        float bias0 = b1[wt * 32 + m], bias1 = b1[wt * 32 + 16 + m];
        #pragma unroll
        for (int mt = 0; mt < 2; mt++) {
            acc[mt][0] = (f4v){bias0, bias0, bias0, bias0};
            acc[mt][1] = (f4v){bias1, bias1, bias1, bias1};
        }
        const ushort* bBase = w1s + wt * 1024 + (size_t)lane * 8;
        #pragma unroll
        for (int kc = 0; kc < 4; kc++) {      // K 0..127 from s_a (h[col])
            s8v b0 = *(const s8v*)(bBase + kc * 4096);
            s8v b1v = *(const s8v*)(bBase + kc * 4096 + 512);
            #pragma unroll
            for (int mt = 0; mt < 2; mt++) {
                s8v a = *(const s8v*)(s_a + (rbase + mt * 16 + m) * EF_STR + kc * 32 + quad * 8);
                acc[mt][0] = __builtin_amdgcn_mfma_f32_16x16x32_bf16(a, b0, acc[mt][0], 0, 0, 0);
                acc[mt][1] = __builtin_amdgcn_mfma_f32_16x16x32_bf16(a, b1v, acc[mt][1], 0, 0, 0);
            }
        }
        #pragma unroll
        for (int kc = 4; kc < 8; kc++) {      // K 128..255 from s_b (h[row])
            s8v b0 = *(const s8v*)(bBase + kc * 4096);
            s8v b1v = *(const s8v*)(bBase + kc * 4096 + 512);
            #pragma unroll
            for (int mt = 0; mt < 2; mt++) {
                s8v a = *(const s8v*)(s_b + (rbase + mt * 16 + m) * EF_STR + (kc - 4) * 32 + quad * 8);
                acc[mt][0] = __builtin_amdgcn_mfma_f32_16x16x32_bf16(a, b0, acc[mt][0], 0, 0, 0);
                acc[mt][1] = __builtin_amdgcn_mfma_f32_16x16x32_bf16(a, b1v, acc[mt][1], 0, 0, 0);
            }
        }
        {                                      // K 256..287 from s_t
            s8v b0 = *(const s8v*)(bBase + 8 * 4096);
            s8v b1v = *(const s8v*)(bBase + 8 * 4096 + 512);
            #pragma unroll
            for (int mt = 0; mt < 2; mt++) {
                s8v a = *(const s8v*)(s_t + (rbase + mt * 16 + m) * TL_STR + quad * 8);
                acc[mt][0] = __builtin_amdgcn_mfma_f32_16x16x32_bf16(a, b0, acc[mt][0], 0, 0, 0);
                acc[mt][1] = __builtin_amdgcn_mfma_f32_16x16x32_bf16(a, b1v, acc[mt][1], 0, 0, 0);
            }
        }
    }
    __syncthreads(); // B2: GEMM1 reads done — s_a reusable

    // epilogue1 → s_a
    #pragma unroll
    for (int tt = 0; tt < 2; tt++) {
        int col = (wt * 2 + tt) * 16 + m;
        #pragma unroll
        for (int mt = 0; mt < 2; mt++)
            #pragma unroll
            for (int r = 0; r < 4; r++)
                s_a[(rbase + mt * 16 + quad * 4 + r) * EF_STR + col] = f2bf_t(silu_f(acc[mt][tt][r]));
    }
    __syncthreads(); // B3: efa ready

    // ---- GEMM2: K=128 from s_a; epilogue → s_b ----
    {
        f4v acc2[2][2];
        float bias0 = b2[wt * 32 + m], bias1 = b2[wt * 32 + 16 + m];
        #pragma unroll
        for (int mt = 0; mt < 2; mt++) {
            acc2[mt][0] = (f4v){bias0, bias0, bias0, bias0};
            acc2[mt][1] = (f4v){bias1, bias1, bias1, bias1};
        }
        const ushort* bBase = w2s + wt * 1024 + (size_t)lane * 8;
        #pragma unroll
        for (int kc = 0; kc < 4; kc++) {
            s8v b0 = *(const s8v*)(bBase + kc * 4096);
            s8v b1v = *(const s8v*)(bBase + kc * 4096 + 512);
            #pragma unroll
            for (int mt = 0; mt < 2; mt++) {
                s8v a = *(const s8v*)(s_a + (rbase + mt * 16 + m) * EF_STR + kc * 32 + quad * 8);
                acc2[mt][0] = __builtin_amdgcn_mfma_f32_16x16x32_bf16(a, b0, acc2[mt][0], 0, 0, 0);
                acc2[mt][1] = __builtin_amdgcn_mfma_f32_16x16x32_bf16(a, b1v, acc2[mt][1], 0, 0, 0);
            }
        }
        #pragma unroll
        for (int tt = 0; tt < 2; tt++) {
            int col = (wt * 2 + tt) * 16 + m;
            #pragma unroll
            for (int mt = 0; mt < 2; mt++)
                #pragma unroll
                for (int r = 0; r < 4; r++)
                    s_b[(rbase + mt * 16 + quad * 4 + r) * EF_STR + col] = f2bf_t(silu_f(acc2[mt][tt][r]));
        }
    }
    __syncthreads(); // B4: efb ready

    // ---- coord gate: partials per wave → s_t (f32 stride 20) ----
    {
        f4v acc3[2][2];
        float bias0 = cb1[wt * 32 + m], bias1 = cb1[wt * 32 + 16 + m];
        float wc0 = cwc[wt * 32 + m],  wc1 = cwc[wt * 32 + 16 + m];
        #pragma unroll
        for (int mt = 0; mt < 2; mt++) {
            acc3[mt][0] = (f4v){bias0, bias0, bias0, bias0};
            acc3[mt][1] = (f4v){bias1, bias1, bias1, bias1};
        }
        const ushort* bBase = cw1s + wt * 1024 + (size_t)lane * 8;
        #pragma unroll
        for (int kc = 0; kc < 4; kc++) {
            s8v b0 = *(const s8v*)(bBase + kc * 4096);
            s8v b1v = *(const s8v*)(bBase + kc * 4096 + 512);
            #pragma unroll
            for (int mt = 0; mt < 2; mt++) {
                s8v a = *(const s8v*)(s_b + (rbase + mt * 16 + m) * EF_STR + kc * 32 + quad * 8);
                acc3[mt][0] = __builtin_amdgcn_mfma_f32_16x16x32_bf16(a, b0, acc3[mt][0], 0, 0, 0);
                acc3[mt][1] = __builtin_amdgcn_mfma_f32_16x16x32_bf16(a, b1v, acc3[mt][1], 0, 0, 0);
            }
        }
        float* s_part = (float*)s_t;   // [edge][slot 0..15], stride 20 floats
        #pragma unroll
        for (int mt = 0; mt < 2; mt++)
            #pragma unroll
            for (int r = 0; r < 4; r++) {
                float p = silu_f(acc3[mt][0][r]) * wc0 + silu_f(acc3[mt][1][r]) * wc1;
                p += __shfl_xor(p, 1, 64);
                p += __shfl_xor(p, 2, 64);
                if ((m & 3) == 0) {
                    int slot = wt * 4 + (m >> 2);
                    s_part[(rbase + mt * 16 + quad * 4 + r) * 20 + slot] = p;
                }
            }
    }
    __syncthreads(); // B5: partials ready

    if (tid < 64) {
        float* s_part = (float*)s_t;
        float cw = 0.0f;
        #pragma unroll
        for (int l = 0; l < 16; l++) cw += s_part[tid * 20 + l];
        int cn = s_col[tid];
        unsafeAtomicAdd(&agg_coord[cn * 3 + 0], s_cd[tid * 3 + 0] * cw);
        unsafeAtomicAdd(&agg_coord[cn * 3 + 1], s_cd[tid * 3 + 1] * cw);
        unsafeAtomicAdd(&agg_coord[cn * 3 + 2], s_cd[tid * 3 + 2] * cw);
    }
    // feature aggregation: 2 segments × 32 edges (threads 0..255) — halves run-atomics
    if (tid < 256) {
        int j = tid & 127;
        int e0 = (tid >> 7) * 32;
        float accv = 0.0f; int cur = s_col[e0];
        #pragma unroll 4
        for (int e = e0; e < e0 + 32; e++) {
            int c = s_col[e]; // wave-uniform
            if (c != cur) {
                unsafeAtomicAdd(&agg_feat[(size_t)cur * 128 + j], accv);
                accv = 0.0f; cur = c;
            }
            accv += bf2f(s_b[e * EF_STR + j]);
        }
        unsafeAtomicAdd(&agg_feat[(size_t)cur * 128 + j], accv);
    }
}

// ---------------- node update (transposed MFMA) + agg re-zero for next layer ----------------
__global__ void __launch_bounds__(512, 6) k_node(
    float* __restrict__ hbuf, ushort* __restrict__ hbf, float* __restrict__ cbuf,
    float* __restrict__ agg_feat, float* __restrict__ agg_coord,
    const int* __restrict__ ecnt,
    const ushort* __restrict__ w1s, const float* __restrict__ b1,
    const ushort* __restrict__ w2s, const float* __restrict__ b2)
{
    __shared__ alignas(16) ushort s_nin[64 * NIN_STR]; // 33792 B
    __shared__ alignas(16) ushort s_t1[64 * EF_STR];   // 17408 B
    const int tid = threadIdx.x;
    const int nb = blockIdx.x * 64;

    #pragma unroll
    for (int i = 0; i < 2; i++) {
        int idx = i * 512 + tid;
        int e = idx >> 4, ch = idx & 15;
        int node = nb + e;
        uint4 v = make_uint4(0, 0, 0, 0);
        if (node < Nn) v = *(const uint4*)(hbf + (size_t)node * 128 + ch * 8);
        *(uint4*)(s_nin + e * NIN_STR + ch * 8) = v;
    }
    #pragma unroll
    for (int i = 0; i < 4; i++) {
        int idx = i * 512 + tid;
        int e = idx >> 5, ch = idx & 31;
        int node = nb + e;
        float4 f = make_float4(0.f, 0.f, 0.f, 0.f);
        if (node < Nn) {
            f = *(const float4*)(agg_feat + (size_t)node * 128 + ch * 4);
            *(float4*)(agg_feat + (size_t)node * 128 + ch * 4) = make_float4(0.f, 0.f, 0.f, 0.f);
        }
        uint2 pk; pk.x = pack2bf_t(f.x, f.y); pk.y = pack2bf_t(f.z, f.w);
        *(uint2*)(s_nin + e * NIN_STR + 128 + ch * 4) = pk;
    }
    if (tid < 64) {
        int n = nb + tid;
        if (n < Nn) {
            float c = (float)ecnt[n]; c = (c < 1.0f) ? 1.0f : c;
            float inv = __fdividef(1.0f, c);
            cbuf[n * 3 + 0] += agg_coord[n * 3 + 0] * inv;
            cbuf[n * 3 + 1] += agg_coord[n * 3 + 1] * inv;
            cbuf[n * 3 + 2] += agg_coord[n * 3 + 2] * inv;
            agg_coord[n * 3 + 0] = 0.f; agg_coord[n * 3 + 1] = 0.f; agg_coord[n * 3 + 2] = 0.f;
        }
    }
    __syncthreads();

    const int lane = tid & 63, wave = tid >> 6;
    const int m = lane & 15, quad = lane >> 4;
    const int ws2 = wave >> 2, wt = wave & 3;
    const int rbase = ws2 * 32;

    // GEMM1^T: K=256 (bias in acc init)
    {
        f4v acc[2][2];
        #pragma unroll
        for (int ct = 0; ct < 2; ct++) {
            float4 bb = *(const float4*)(b1 + (wt * 2 + ct) * 16 + quad * 4);
            acc[0][ct] = (f4v){bb.x, bb.y, bb.z, bb.w};
            acc[1][ct] = acc[0][ct];
        }
        const ushort* aBase = w1s + wt * 1024 + (size_t)lane * 8;
        #pragma unroll
        for (int kc = 0; kc < 8; kc++) {
            s8v a0 = *(const s8v*)(aBase + kc * 4096);
            s8v a1 = *(const s8v*)(aBase + kc * 4096 + 512);
            #pragma unroll
            for (int nt = 0; nt < 2; nt++) {
                s8v bf = *(const s8v*)(s_nin + (rbase + nt * 16 + m) * NIN_STR + kc * 32 + quad * 8);
                acc[nt][0] = __builtin_amdgcn_mfma_f32_16x16x32_bf16(a0, bf, acc[nt][0], 0, 0, 0);
                acc[nt][1] = __builtin_amdgcn_mfma_f32_16x16x32_bf16(a1, bf, acc[nt][1], 0, 0, 0);
            }
        }
        #pragma unroll
        for (int nt = 0; nt < 2; nt++) {
            int row = rbase + nt * 16 + m;
            #pragma unroll
            for (int ct = 0; ct < 2; ct++) {
                int colb = (wt * 2 + ct) * 16 + quad * 4;
                float v0 = silu_f(acc[nt][ct][0]);
                float v1 = silu_f(acc[nt][ct][1]);
                float v2 = silu_f(acc[nt][ct][2]);
                float v3 = silu_f(acc[nt][ct][3]);
                uint2 pk; pk.x = pack2bf_t(v0, v1); pk.y = pack2bf_t(v2, v3);
                *(uint2*)(s_t1 + row * EF_STR + colb) = pk;
            }
        }
    }
    __syncthreads();

    // GEMM2^T: K=128, residual epilogue (bias in acc init)
    {
        f4v acc[2][2];
        #pragma unroll
        for (int ct = 0; ct < 2; ct++) {
            float4 bb = *(const float4*)(b2 + (wt * 2 + ct) * 16 + quad * 4);
            acc[0][ct] = (f4v){bb.x, bb.y, bb.z, bb.w};
            acc[1][ct] = acc[0][ct];
        }
        const ushort* aBase = w2s + wt * 1024 + (size_t)lane * 8;
        #pragma unroll
        for (int kc = 0; kc < 4; kc++) {
            s8v a0 = *(const s8v*)(aBase + kc * 4096);
            s8v a1 = *(const s8v*)(aBase + kc * 4096 + 512);
            #pragma unroll
            for (int nt = 0; nt < 2; nt++) {
                s8v bf = *(const s8v*)(s_t1 + (rbase + nt * 16 + m) * EF_STR + kc * 32 + quad * 8);
                acc[nt][0] = __builtin_amdgcn_mfma_f32_16x16x32_bf16(a0, bf, acc[nt][0], 0, 0, 0);
                acc[nt][1] = __builtin_amdgcn_mfma_f32_16x16x32_bf16(a1, bf, acc[nt][1], 0, 0, 0);
            }
        }
        #pragma unroll
        for (int nt = 0; nt < 2; nt++) {
            int node = nb + rbase + nt * 16 + m;
            if (node < Nn) {
                #pragma unroll
                for (int ct = 0; ct < 2; ct++) {
                    int colb = (wt * 2 + ct) * 16 + quad * 4;
                    float4 old = *(const float4*)(hbuf + (size_t)node * 128 + colb);
                    float v0 = old.x + acc[nt][ct][0];
                    float v1 = old.y + acc[nt][ct][1];
                    float v2 = old.z + acc[nt][ct][2];
                    float v3 = old.w + acc[nt][ct][3];
                    *(float4*)(hbuf + (size_t)node * 128 + colb) = make_float4(v0, v1, v2, v3);
                    uint2 pk; pk.x = pack2bf_r(v0, v1); pk.y = pack2bf_r(v2, v3);
                    *(uint2*)(hbf + (size_t)node * 128 + colb) = pk;
                }
            }
        }
    }
}

// ---------------- output embedding (transposed MFMA) + coords out ----------------
__global__ void __launch_bounds__(512, 2) k_emb_out(
    const ushort* __restrict__ hbf, const float* __restrict__ cbuf,
    const ushort* __restrict__ ws_, const float* __restrict__ b, float* __restrict__ out)
{
    __shared__ alignas(16) ushort s_h[64 * EF_STR];
    const int tid = threadIdx.x;
    const int nb = blockIdx.x * 64;
    #pragma unroll
    for (int i = 0; i < 2; i++) {
        int idx = i * 512 + tid;
        int e = idx >> 4, ch = idx & 15;
        int node = nb + e;
        uint4 v = make_uint4(0, 0, 0, 0);
        if (node < Nn) v = *(const uint4*)(hbf + (size_t)node * 128 + ch * 8);
        *(uint4*)(s_h + e * EF_STR + ch * 8) = v;
    }
    if (tid < 192) {
        int n = nb + tid / 3, d = tid % 3;
        if (n < Nn) out[(size_t)Nn * 128 + n * 3 + d] = cbuf[n * 3 + d];
    }
    __syncthreads();
    const int lane = tid & 63, wave = tid >> 6;
    const int m = lane & 15, quad = lane >> 4;
    const int ws2 = wave >> 2, wt = wave & 3;
    const int rbase = ws2 * 32;
    f4v acc[2][2];
    #pragma unroll
    for (int ct = 0; ct < 2; ct++) {
        float4 bb = *(const float4*)(b + (wt * 2 + ct) * 16 + quad * 4);
        acc[0][ct] = (f4v){bb.x, bb.y, bb.z, bb.w};
        acc[1][ct] = acc[0][ct];
    }
    const ushort* aBase = ws_ + wt * 1024 + (size_t)lane * 8;
    #pragma unroll
    for (int kc = 0; kc < 4; kc++) {
        s8v a0 = *(const s8v*)(aBase + kc * 4096);
        s8v a1 = *(const s8v*)(aBase + kc * 4096 + 512);
        #pragma unroll
        for (int nt = 0; nt < 2; nt++) {
            s8v bf = *(const s8v*)(s_h + (rbase + nt * 16 + m) * EF_STR + kc * 32 + quad * 8);
            acc[nt][0] = __builtin_amdgcn_mfma_f32_16x16x32_bf16(a0, bf, acc[nt][0], 0, 0, 0);
            acc[nt][1] = __builtin_amdgcn_mfma_f32_16x16x32_bf16(a1, bf, acc[nt][1], 0, 0, 0);
        }
    }
    #pragma unroll
    for (int nt = 0; nt < 2; nt++) {
        int node = nb + rbase + nt * 16 + m;
        if (node < Nn) {
            #pragma unroll
            for (int ct = 0; ct < 2; ct++) {
                int colb = (wt * 2 + ct) * 16 + quad * 4;
                float4 o = make_float4(acc[nt][ct][0], acc[nt][ct][1],
                                       acc[nt][ct][2], acc[nt][ct][3]);
                *(float4*)(out + (size_t)node * 128 + colb) = o;
            }
        }
    }
}

// ---------------- host launcher ----------------
extern "C" void kernel_launch(void* const* d_in, const int* in_sizes, int n_in,
                              void* d_out, int out_size, void* d_ws, size_t ws_size,
                              hipStream_t stream)
{
    const float* h_in      = (const float*)d_in[0];
    const float* coords    = (const float*)d_in[1];
    const float* edge_attr = (const float*)d_in[2];
    const float* emb_in_W  = (const float*)d_in[3];
    const float* emb_in_b  = (const float*)d_in[4];
    const float* emb_out_W = (const float*)d_in[5];
    const float* emb_out_b = (const float*)d_in[6];
    const float* eW1 = (const float*)d_in[7];
    const float* eb1 = (const float*)d_in[8];
    const float* eW2 = (const float*)d_in[9];
    const float* eb2 = (const float*)d_in[10];
    const float* cW1 = (const float*)d_in[11];
    const float* cb1 = (const float*)d_in[12];
    const float* cWc = (const float*)d_in[13];
    const float* nW1 = (const float*)d_in[14];
    const float* nb1 = (const float*)d_in[15];
    const float* nW2 = (const float*)d_in[16];
    const float* nb2 = (const float*)d_in[17];
    const int*  eidx = (const int*)d_in[18];

    size_t off = 0;
    char* base = (char*)d_ws;
    auto alloc = [&](size_t bytes) -> char* {
        char* p = base + off;
        off += (bytes + 255) & ~(size_t)255;
        return p;
    };
    float*  hbuf      = (float*)alloc((size_t)Nn * 128 * 4);
    ushort* hbf       = (ushort*)alloc((size_t)Nn * 128 * 2);
    float*  cbuf      = (float*)alloc((size_t)Nn * 3 * 4);
    int*    ecnt      = (int*)alloc((size_t)Nn * 4);
    int*    cursor    = (int*)alloc((size_t)Nn * 4);
    int*    bsum      = (int*)alloc((size_t)NB_SCAN * 4);
    int*    srow      = (int*)alloc((size_t)Ee * 4);
    int*    scol      = (int*)alloc((size_t)Ee * 4);
    float*  sattr     = (float*)alloc((size_t)Ee * 4);
    float*  agg_feat  = (float*)alloc((size_t)Nn * 128 * 4);
    float*  agg_coord = (float*)alloc((size_t)Nn * 3 * 4);
    ushort* eW1s      = (ushort*)alloc((size_t)4 * 36864 * 2);
    ushort* eW2s      = (ushort*)alloc((size_t)4 * 16384 * 2);
    ushort* cW1s      = (ushort*)alloc((size_t)4 * 16384 * 2);
    ushort* nW1s      = (ushort*)alloc((size_t)4 * 32768 * 2);
    ushort* nW2s      = (ushort*)alloc((size_t)4 * 16384 * 2);
    ushort* eInWs     = (ushort*)alloc((size_t)8192 * 2);
    ushort* eOutWs    = (ushort*)alloc((size_t)16384 * 2);

    k_swz_all<<<499712 / 256, 256, 0, stream>>>(
        eW1, eW2, cW1, nW1, nW2, emb_in_W, emb_out_W,
        eW1s, eW2s, cW1s, nW1s, nW2s, eInWs, eOutWs);

    hipMemsetAsync(ecnt, 0, (size_t)Nn * 4, stream);
    k_count<<<Ee / 256, 256, 0, stream>>>(eidx, ecnt);
    k_bsum<<<NB_SCAN, 256, 0, stream>>>(ecnt, bsum);
    k_bscan<<<1, 256, 0, stream>>>(bsum);
    k_cursor<<<NB_SCAN, 256, 0, stream>>>(ecnt, bsum, cursor);
    k_scatter<<<Ee / 256, 256, 0, stream>>>(eidx, edge_attr, cursor, srow, scol, sattr);
    k_emb<<<(Nn + 63) / 64, 512, 0, stream>>>(h_in, coords, eInWs, emb_in_b, hbuf, hbf, cbuf);

    // zero agg buffers once; k_node re-zeroes them for the next layer
    hipMemsetAsync(agg_feat, 0, (size_t)Nn * 128 * 4, stream);
    hipMemsetAsync(agg_coord, 0, (size_t)Nn * 3 * 4, stream);

    for (int l = 0; l < 4; l++) {
        k_edge<<<Ee / 64, 512, 0, stream>>>(
            hbf, cbuf, srow, scol, sattr,
            eW1s + (size_t)l * 36864, eb1 + l * 128,
            eW2s + (size_t)l * 16384, eb2 + l * 128,
            cW1s + (size_t)l * 16384, cb1 + l * 128,
            cWc + l * 128,
            agg_feat, agg_coord);
        k_node<<<(Nn + 63) / 64, 512, 0, stream>>>(
            hbuf, hbf, cbuf, agg_feat, agg_coord, ecnt,
            nW1s + (size_t)l * 32768, nb1 + l * 128,
            nW2s + (size_t)l * 16384, nb2 + l * 128);
    }
    k_emb_out<<<(Nn + 63) / 64, 512, 0, stream>>>(hbf, cbuf, eOutWs, emb_out_b, (float*)d_out);
}

// Round 8
// 1646.720 us; speedup vs baseline: 1.1154x; 1.0181x over previous
//
#include <hip/hip_runtime.h>

// ---------------- problem constants ----------------
constexpr int Nn = 50000;
constexpr int Ee = 800000;
constexpr int EF_STR  = 136; // 68 dw
constexpr int NIN_STR = 264; // 132 dw
constexpr int HIN_STR = 72;  // 36 dw
constexpr int NB_SCAN = (Nn + 255) / 256; // 196

typedef short s8v __attribute__((ext_vector_type(8)));
typedef float f4v __attribute__((ext_vector_type(4)));

__device__ __forceinline__ ushort f2bf(float f) {      // RNE
    uint u = __float_as_uint(f);
    uint r = (u + 0x7FFFu + ((u >> 16) & 1u)) >> 16;
    return (ushort)r;
}
__device__ __forceinline__ ushort f2bf_t(float f) {    // truncate (hot paths)
    return (ushort)(__float_as_uint(f) >> 16);
}
__device__ __forceinline__ float bf2f(ushort s) {
    return __uint_as_float(((uint)s) << 16);
}
__device__ __forceinline__ float silu_f(float x) {
    return x * __fdividef(1.0f, 1.0f + __expf(-x));
}
__device__ __forceinline__ uint pack2bf_t(float lo, float hi) {
    return __builtin_amdgcn_perm(__float_as_uint(hi), __float_as_uint(lo), 0x07060302u);
}
__device__ __forceinline__ uint pack2bf_r(float lo, float hi) {
    uint a = __float_as_uint(lo) + 0x8000u;
    uint b = __float_as_uint(hi) + 0x8000u;
    return __builtin_amdgcn_perm(b, a, 0x07060302u);
}

// ---------------- merged weight pre-swizzle ----------------
// element = src[l*lstride + k*128 + n] (k<K else 0); dst [L,KC,t(8),lane(64),j(8)]
__device__ __forceinline__ void swz_one(const float* src, ushort* dst, int K, int lstride, int KC, int idx)
{
    int per = KC * 4096;
    int l = idx / per, r = idx % per;
    int fb = r >> 9, rem = r & 511;
    int lane = rem >> 3, jj = rem & 7;
    int kc = fb >> 3, t = fb & 7;
    int k = kc * 32 + ((lane >> 4) << 3) + jj;
    int n = t * 16 + (lane & 15);
    float v = (k < K) ? src[(size_t)l * lstride + (size_t)k * 128 + n] : 0.0f;
    dst[idx] = f2bf(v);
}
__global__ void __launch_bounds__(256) k_swz_all(
    const float* __restrict__ eW1, const float* __restrict__ eW2, const float* __restrict__ cW1,
    const float* __restrict__ nW1, const float* __restrict__ nW2,
    const float* __restrict__ inW, const float* __restrict__ outW,
    ushort* __restrict__ oT, ushort* __restrict__ oM,
    ushort* __restrict__ o2, ushort* __restrict__ o3,
    ushort* __restrict__ o4, ushort* __restrict__ o5,
    ushort* __restrict__ o6, ushort* __restrict__ o7)
{
    int gid = blockIdx.x * 256 + threadIdx.x;
    if (gid < 65536)       swz_one(eW1,         oT, 128, 33024, 4, gid);           // W1_top
    else if (gid < 131072) swz_one(eW1 + 16384, oM, 128, 33024, 4, gid - 65536);   // W1_mid
    else if (gid < 196608) swz_one(eW2, o2, 128, 16384, 4, gid - 131072);
    else if (gid < 262144) swz_one(cW1, o3, 128, 16384, 4, gid - 196608);
    else if (gid < 393216) swz_one(nW1, o4, 256, 32768, 8, gid - 262144);
    else if (gid < 458752) swz_one(nW2, o5, 128, 16384, 4, gid - 393216);
    else if (gid < 466944) swz_one(inW, o6, 64, 8192, 2, gid - 458752);
    else if (gid < 483328) swz_one(outW, o7, 128, 16384, 4, gid - 466944);
}

// ---------------- incoming-edge histogram ----------------
__global__ void __launch_bounds__(256) k_count(const int* __restrict__ eidx, int* __restrict__ ecnt)
{
    int e = blockIdx.x * 256 + threadIdx.x;
    atomicAdd(&ecnt[eidx[Ee + e]], 1);
}

// ---------------- multi-block exclusive scan (3 passes) ----------------
__global__ void __launch_bounds__(256) k_bsum(const int* __restrict__ ecnt, int* __restrict__ bsum)
{
    __shared__ int ws[4];
    int tid = threadIdx.x, lane = tid & 63, w = tid >> 6;
    int i = blockIdx.x * 256 + tid;
    int x = (i < Nn) ? ecnt[i] : 0;
    #pragma unroll
    for (int off = 1; off < 64; off <<= 1) x += __shfl_xor(x, off, 64);
    if (lane == 0) ws[w] = x;
    __syncthreads();
    if (tid == 0) bsum[blockIdx.x] = ws[0] + ws[1] + ws[2] + ws[3];
}
__global__ void __launch_bounds__(256) k_bscan(int* __restrict__ bsum)
{
    __shared__ int ws[4];
    int tid = threadIdx.x, lane = tid & 63, w = tid >> 6;
    int x = (tid < NB_SCAN) ? bsum[tid] : 0;
    int s = x;
    #pragma unroll
    for (int off = 1; off < 64; off <<= 1) {
        int t = __shfl_up(s, off, 64);
        if (lane >= off) s += t;
    }
    if (lane == 63) ws[w] = s;
    __syncthreads();
    if (tid == 0) { int a = 0; for (int k = 0; k < 4; k++) { int t = ws[k]; ws[k] = a; a += t; } }
    __syncthreads();
    int excl = ws[w] + s - x;
    if (tid < NB_SCAN) bsum[tid] = excl;
}
__global__ void __launch_bounds__(256) k_cursor(const int* __restrict__ ecnt,
                                               const int* __restrict__ boff, int* __restrict__ cursor)
{
    __shared__ int ws[4];
    int tid = threadIdx.x, lane = tid & 63, w = tid >> 6;
    int i = blockIdx.x * 256 + tid;
    int x = (i < Nn) ? ecnt[i] : 0;
    int s = x;
    #pragma unroll
    for (int off = 1; off < 64; off <<= 1) {
        int t = __shfl_up(s, off, 64);
        if (lane >= off) s += t;
    }
    if (lane == 63) ws[w] = s;
    __syncthreads();
    if (tid == 0) { int a = 0; for (int k = 0; k < 4; k++) { int t = ws[k]; ws[k] = a; a += t; } }
    __syncthreads();
    int excl = ws[w] + s - x + boff[blockIdx.x];
    if (i < Nn) cursor[i] = excl;
}

// ---------------- scatter edges into col-sorted arrays ----------------
__global__ void __launch_bounds__(256) k_scatter(
    const int* __restrict__ eidx, const float* __restrict__ edge_attr,
    int* __restrict__ cursor,
    int* __restrict__ srow, int* __restrict__ scol, float* __restrict__ sattr)
{
    int e = blockIdx.x * 256 + threadIdx.x;
    int r = eidx[e], c = eidx[Ee + e];
    int p = atomicAdd(&cursor[c], 1);
    srow[p] = r; scol[p] = c; sattr[p] = edge_attr[e];
}

// ---------------- input embedding (transposed MFMA, K=64) + coord copy ----------------
__global__ void __launch_bounds__(512, 2) k_emb(
    const float* __restrict__ h_in, const float* __restrict__ coords,
    const ushort* __restrict__ ws_, const float* __restrict__ b,
    float* __restrict__ hbuf, ushort* __restrict__ hbf, float* __restrict__ cbuf)
{
    __shared__ alignas(16) ushort s_h[64 * HIN_STR];
    const int tid = threadIdx.x;
    const int nb = blockIdx.x * 64;
    #pragma unroll
    for (int i = 0; i < 2; i++) {
        int idx = i * 512 + tid;
        int e = idx >> 4, ch = idx & 15;
        int node = nb + e;
        float4 f = make_float4(0.f, 0.f, 0.f, 0.f);
        if (node < Nn) f = *(const float4*)(h_in + (size_t)node * 64 + ch * 4);
        ushort4 u; u.x = f2bf(f.x); u.y = f2bf(f.y); u.z = f2bf(f.z); u.w = f2bf(f.w);
        *(ushort4*)(s_h + e * HIN_STR + ch * 4) = u;
    }
    if (tid < 192) {
        int n = nb + tid / 3, d = tid % 3;
        if (n < Nn) cbuf[n * 3 + d] = coords[n * 3 + d];
    }
    __syncthreads();
    const int lane = tid & 63, wave = tid >> 6;
    const int m = lane & 15, quad = lane >> 4;
    const int ws2 = wave >> 2, wt = wave & 3;
    const int rbase = ws2 * 32;
    f4v acc[2][2];
    #pragma unroll
    for (int nt = 0; nt < 2; nt++) { acc[nt][0] = (f4v){0,0,0,0}; acc[nt][1] = (f4v){0,0,0,0}; }
    const ushort* aBase = ws_ + wt * 1024 + lane * 8;
    #pragma unroll
    for (int kc = 0; kc < 2; kc++) {
        s8v a0 = *(const s8v*)(aBase + kc * 4096);
        s8v a1 = *(const s8v*)(aBase + kc * 4096 + 512);
        #pragma unroll
        for (int nt = 0; nt < 2; nt++) {
            s8v bf = *(const s8v*)(s_h + (rbase + nt * 16 + m) * HIN_STR + kc * 32 + quad * 8);
            acc[nt][0] = __builtin_amdgcn_mfma_f32_16x16x32_bf16(a0, bf, acc[nt][0], 0, 0, 0);
            acc[nt][1] = __builtin_amdgcn_mfma_f32_16x16x32_bf16(a1, bf, acc[nt][1], 0, 0, 0);
        }
    }
    #pragma unroll
    for (int nt = 0; nt < 2; nt++) {
        int node = nb + rbase + nt * 16 + m;
        if (node < Nn) {
            #pragma unroll
            for (int ct = 0; ct < 2; ct++) {
                int colb = (wt * 2 + ct) * 16 + quad * 4;
                float4 bb = *(const float4*)(b + colb);
                float v0 = acc[nt][ct][0] + bb.x;
                float v1 = acc[nt][ct][1] + bb.y;
                float v2 = acc[nt][ct][2] + bb.z;
                float v3 = acc[nt][ct][3] + bb.w;
                *(float4*)(hbuf + (size_t)node * 128 + colb) = make_float4(v0, v1, v2, v3);
                uint2 pk; pk.x = pack2bf_r(v0, v1); pk.y = pack2bf_r(v2, v3);
                *(uint2*)(hbf + (size_t)node * 128 + colb) = pk;
            }
        }
    }
}

// ---------------- per-layer U/V precompute: U = h@W1_top + b1, V = h@W1_mid ----------------
// uvb[n][0..127] = U (bf16 RNE), uvb[n][128..255] = V
__global__ void __launch_bounds__(512, 2) k_uv(
    const ushort* __restrict__ hbf,
    const ushort* __restrict__ topW, const ushort* __restrict__ midW,
    const float* __restrict__ b1, ushort* __restrict__ uvb)
{
    __shared__ alignas(16) ushort s_h[64 * EF_STR];
    const int tid = threadIdx.x;
    const int nb = blockIdx.x * 64;
    #pragma unroll
    for (int i = 0; i < 2; i++) {
        int idx = i * 512 + tid;
        int e = idx >> 4, ch = idx & 15;
        int node = nb + e;
        uint4 v = make_uint4(0, 0, 0, 0);
        if (node < Nn) v = *(const uint4*)(hbf + (size_t)node * 128 + ch * 8);
        *(uint4*)(s_h + e * EF_STR + ch * 8) = v;
    }
    __syncthreads();
    const int lane = tid & 63, wave = tid >> 6;
    const int m = lane & 15, quad = lane >> 4;
    const int ws2 = wave >> 2, wt = wave & 3;
    const int rbase = ws2 * 32;
    f4v au[2][2], av[2][2];
    #pragma unroll
    for (int ct = 0; ct < 2; ct++) {
        float4 bb = *(const float4*)(b1 + (wt * 2 + ct) * 16 + quad * 4);
        au[0][ct] = (f4v){bb.x, bb.y, bb.z, bb.w};
        au[1][ct] = au[0][ct];
        av[0][ct] = (f4v){0,0,0,0};
        av[1][ct] = (f4v){0,0,0,0};
    }
    const ushort* tBase = topW + wt * 1024 + (size_t)lane * 8;
    const ushort* mBase = midW + wt * 1024 + (size_t)lane * 8;
    #pragma unroll
    for (int kc = 0; kc < 4; kc++) {
        s8v t0 = *(const s8v*)(tBase + kc * 4096);
        s8v t1 = *(const s8v*)(tBase + kc * 4096 + 512);
        s8v m0 = *(const s8v*)(mBase + kc * 4096);
        s8v m1 = *(const s8v*)(mBase + kc * 4096 + 512);
        #pragma unroll
        for (int nt = 0; nt < 2; nt++) {
            s8v bf = *(const s8v*)(s_h + (rbase + nt * 16 + m) * EF_STR + kc * 32 + quad * 8);
            au[nt][0] = __builtin_amdgcn_mfma_f32_16x16x32_bf16(t0, bf, au[nt][0], 0, 0, 0);
            au[nt][1] = __builtin_amdgcn_mfma_f32_16x16x32_bf16(t1, bf, au[nt][1], 0, 0, 0);
            av[nt][0] = __builtin_amdgcn_mfma_f32_16x16x32_bf16(m0, bf, av[nt][0], 0, 0, 0);
            av[nt][1] = __builtin_amdgcn_mfma_f32_16x16x32_bf16(m1, bf, av[nt][1], 0, 0, 0);
        }
    }
    #pragma unroll
    for (int nt = 0; nt < 2; nt++) {
        int node = nb + rbase + nt * 16 + m;
        if (node < Nn) {
            #pragma unroll
            for (int ct = 0; ct < 2; ct++) {
                int colb = (wt * 2 + ct) * 16 + quad * 4;
                uint2 pu; pu.x = pack2bf_r(au[nt][ct][0], au[nt][ct][1]);
                          pu.y = pack2bf_r(au[nt][ct][2], au[nt][ct][3]);
                *(uint2*)(uvb + (size_t)node * 256 + colb) = pu;
                uint2 pv; pv.x = pack2bf_r(av[nt][ct][0], av[nt][ct][1]);
                          pv.y = pack2bf_r(av[nt][ct][2], av[nt][ct][3]);
                *(uint2*)(uvb + (size_t)node * 256 + 128 + colb) = pv;
            }
        }
    }
}

// ---------------- fused edge kernel: gather-add ef1 + GEMM2 + coord gate + aggregation ----
// ef1 = silu(U[col] + V[row] + dist*Wd + attr*Wa)  — GEMM1 hoisted to k_uv.
// LDS = 40960 B exactly → 4 blocks/CU.
__global__ void __launch_bounds__(512, 8) k_edge(
    const float* __restrict__ cbuf,
    const int* __restrict__ srow, const int* __restrict__ scol, const float* __restrict__ sattr,
    const ushort* __restrict__ uvb,
    const float* __restrict__ wd, const float* __restrict__ wa,
    const ushort* __restrict__ w2s, const float* __restrict__ b2,
    const ushort* __restrict__ cw1s, const float* __restrict__ cb1,
    const float* __restrict__ cwc,
    float* __restrict__ agg_feat, float* __restrict__ agg_coord)
{
    __shared__ alignas(16) ushort s_a[64 * EF_STR];  // ef1
    __shared__ alignas(16) ushort s_b[64 * EF_STR];  // efb
    __shared__ alignas(16) float  s_t[64 * 20];      // slots 0-15: coord partials; 16=dist,17=attr,18=row
    __shared__ int   s_col[64];
    __shared__ float s_cd[64 * 3];

    const int tid = threadIdx.x;
    const int eb = blockIdx.x * 64;

    // phase 0: edge metadata
    if (tid < 64) {
        int rw = srow[eb + tid], cl = scol[eb + tid];
        s_col[tid] = cl;
        float d0 = cbuf[rw * 3 + 0] - cbuf[cl * 3 + 0];
        float d1 = cbuf[rw * 3 + 1] - cbuf[cl * 3 + 1];
        float d2 = cbuf[rw * 3 + 2] - cbuf[cl * 3 + 2];
        s_cd[tid * 3 + 0] = d0; s_cd[tid * 3 + 1] = d1; s_cd[tid * 3 + 2] = d2;
        s_t[tid * 20 + 16] = d0 * d0 + d1 * d1 + d2 * d2;
        s_t[tid * 20 + 17] = sattr[eb + tid];
        s_t[tid * 20 + 18] = __int_as_float(rw);
    }
    __syncthreads(); // B0: metadata ready

    // phase 1: ef1 gather-add (each thread: one edge × 16 cols)
    {
        const int e = tid >> 3, ch = tid & 7;
        float dist = s_t[e * 20 + 16];
        float attr = s_t[e * 20 + 17];
        int row = __float_as_int(s_t[e * 20 + 18]);
        int col = s_col[e];
        const ushort* up = uvb + (size_t)col * 256 + ch * 16;
        const ushort* vp = uvb + (size_t)row * 256 + 128 + ch * 16;
        uint4 ua = *(const uint4*)up;
        uint4 ub = *(const uint4*)(up + 8);
        uint4 va = *(const uint4*)vp;
        uint4 vb = *(const uint4*)(vp + 8);
        float4 wdv[4], wav[4];
        #pragma unroll
        for (int i = 0; i < 4; i++) {
            wdv[i] = *(const float4*)(wd + ch * 16 + i * 4);
            wav[i] = *(const float4*)(wa + ch * 16 + i * 4);
        }
        const float* wdf = (const float*)wdv;
        const float* waf = (const float*)wav;
        uint uu[8] = {ua.x, ua.y, ua.z, ua.w, ub.x, ub.y, ub.z, ub.w};
        uint vv[8] = {va.x, va.y, va.z, va.w, vb.x, vb.y, vb.z, vb.w};
        uint pk[8];
        #pragma unroll
        for (int p = 0; p < 8; p++) {
            float ulo = __uint_as_float(uu[p] << 16);
            float uhi = __uint_as_float(uu[p] & 0xFFFF0000u);
            float vlo = __uint_as_float(vv[p] << 16);
            float vhi = __uint_as_float(vv[p] & 0xFFFF0000u);
            float lo = ulo + vlo + dist * wdf[2 * p] + attr * waf[2 * p];
            float hi = uhi + vhi + dist * wdf[2 * p + 1] + attr * waf[2 * p + 1];
            pk[p] = pack2bf_t(silu_f(lo), silu_f(hi));
        }
        *(uint4*)(s_a + e * EF_STR + ch * 16) = make_uint4(pk[0], pk[1], pk[2], pk[3]);
        *(uint4*)(s_a + e * EF_STR + ch * 16 + 8) = make_uint4(pk[4], pk[5], pk[6], pk[7]);
    }
    __syncthreads(); // B1: ef1 ready

    const int lane = tid & 63, wave = tid >> 6;
    const int m = lane & 15, quad = lane >> 4;
    const int ws2 = wave >> 2, wt = wave & 3;
    const int rbase = ws2 * 32;

    // ---- GEMM2: K=128 from s_a; epilogue → s_b ----
    {
        f4v acc2[2][2];
        float bias0 = b2[wt * 32 + m], bias1 = b2[wt * 32 + 16 + m];
        #pragma unroll
        for (int mt = 0; mt < 2; mt++) {
            acc2[mt][0] = (f4v){bias0, bias0, bias0, bias0};
            acc2[mt][1] = (f4v){bias1, bias1, bias1, bias1};
        }
        const ushort* bBase = w2s + wt * 1024 + (size_t)lane * 8;
        #pragma unroll
        for (int kc = 0; kc < 4; kc++) {
            s8v b0 = *(const s8v*)(bBase + kc * 4096);
            s8v b1v = *(const s8v*)(bBase + kc * 4096 + 512);
            #pragma unroll
            for (int mt = 0; mt < 2; mt++) {
                s8v a = *(const s8v*)(s_a + (rbase + mt * 16 + m) * EF_STR + kc * 32 + quad * 8);
                acc2[mt][0] = __builtin_amdgcn_mfma_f32_16x16x32_bf16(a, b0, acc2[mt][0], 0, 0, 0);
                acc2[mt][1] = __builtin_amdgcn_mfma_f32_16x16x32_bf16(a, b1v, acc2[mt][1], 0, 0, 0);
            }
        }
        #pragma unroll
        for (int tt = 0; tt < 2; tt++) {
            int col = (wt * 2 + tt) * 16 + m;
            #pragma unroll
            for (int mt = 0; mt < 2; mt++)
                #pragma unroll
                for (int r = 0; r < 4; r++)
                    s_b[(rbase + mt * 16 + quad * 4 + r) * EF_STR + col] = f2bf_t(silu_f(acc2[mt][tt][r]));
        }
    }
    __syncthreads(); // B2: efb ready

    // ---- coord gate: partials per wave → s_t slots 0..15 ----
    {
        f4v acc3[2][2];
        float bias0 = cb1[wt * 32 + m], bias1 = cb1[wt * 32 + 16 + m];
        float wc0 = cwc[wt * 32 + m],  wc1 = cwc[wt * 32 + 16 + m];
        #pragma unroll
        for (int mt = 0; mt < 2; mt++) {
            acc3[mt][0] = (f4v){bias0, bias0, bias0, bias0};
            acc3[mt][1] = (f4v){bias1, bias1, bias1, bias1};
        }
        const ushort* bBase = cw1s + wt * 1024 + (size_t)lane * 8;
        #pragma unroll
        for (int kc = 0; kc < 4; kc++) {
            s8v b0 = *(const s8v*)(bBase + kc * 4096);
            s8v b1v = *(const s8v*)(bBase + kc * 4096 + 512);
            #pragma unroll
            for (int mt = 0; mt < 2; mt++) {
                s8v a = *(const s8v*)(s_b + (rbase + mt * 16 + m) * EF_STR + kc * 32 + quad * 8);
                acc3[mt][0] = __builtin_amdgcn_mfma_f32_16x16x32_bf16(a, b0, acc3[mt][0], 0, 0, 0);
                acc3[mt][1] = __builtin_amdgcn_mfma_f32_16x16x32_bf16(a, b1v, acc3[mt][1], 0, 0, 0);
            }
        }
        #pragma unroll
        for (int mt = 0; mt < 2; mt++)
            #pragma unroll
            for (int r = 0; r < 4; r++) {
                float p = silu_f(acc3[mt][0][r]) * wc0 + silu_f(acc3[mt][1][r]) * wc1;
                p += __shfl_xor(p, 1, 64);
                p += __shfl_xor(p, 2, 64);
                if ((m & 3) == 0) {
                    int slot = wt * 4 + (m >> 2);
                    s_t[(rbase + mt * 16 + quad * 4 + r) * 20 + slot] = p;
                }
            }
    }
    __syncthreads(); // B3: partials ready

    if (tid < 64) {
        float cw = 0.0f;
        #pragma unroll
        for (int l = 0; l < 16; l++) cw += s_t[tid * 20 + l];
        int cn = s_col[tid];
        unsafeAtomicAdd(&agg_coord[cn * 3 + 0], s_cd[tid * 3 + 0] * cw);
        unsafeAtomicAdd(&agg_coord[cn * 3 + 1], s_cd[tid * 3 + 1] * cw);
        unsafeAtomicAdd(&agg_coord[cn * 3 + 2], s_cd[tid * 3 + 2] * cw);
    }
    // feature aggregation: 2 segments × 32 edges, run-length reduced
    if (tid < 256) {
        int j = tid & 127;
        int e0 = (tid >> 7) * 32;
        float accv = 0.0f; int cur = s_col[e0];
        #pragma unroll 4
        for (int e = e0; e < e0 + 32; e++) {
            int c = s_col[e];
            if (c != cur) {
                unsafeAtomicAdd(&agg_feat[(size_t)cur * 128 + j], accv);
                accv = 0.0f; cur = c;
            }
            accv += bf2f(s_b[e * EF_STR + j]);
        }
        unsafeAtomicAdd(&agg_feat[(size_t)cur * 128 + j], accv);
    }
}

// ---------------- node update (transposed MFMA) + agg re-zero for next layer ----------------
__global__ void __launch_bounds__(512, 6) k_node(
    float* __restrict__ hbuf, ushort* __restrict__ hbf, float* __restrict__ cbuf,
    float* __restrict__ agg_feat, float* __restrict__ agg_coord,
    const int* __restrict__ ecnt,
    const ushort* __restrict__ w1s, const float* __restrict__ b1,
    const ushort* __restrict__ w2s, const float* __restrict__ b2)
{
    __shared__ alignas(16) ushort s_nin[64 * NIN_STR];
    __shared__ alignas(16) ushort s_t1[64 * EF_STR];
    const int tid = threadIdx.x;
    const int nb = blockIdx.x * 64;

    #pragma unroll
    for (int i = 0; i < 2; i++) {
        int idx = i * 512 + tid;
        int e = idx >> 4, ch = idx & 15;
        int node = nb + e;
        uint4 v = make_uint4(0, 0, 0, 0);
        if (node < Nn) v = *(const uint4*)(hbf + (size_t)node * 128 + ch * 8);
        *(uint4*)(s_nin + e * NIN_STR + ch * 8) = v;
    }
    #pragma unroll
    for (int i = 0; i < 4; i++) {
        int idx = i * 512 + tid;
        int e = idx >> 5, ch = idx & 31;
        int node = nb + e;
        float4 f = make_float4(0.f, 0.f, 0.f, 0.f);
        if (node < Nn) {
            f = *(const float4*)(agg_feat + (size_t)node * 128 + ch * 4);
            *(float4*)(agg_feat + (size_t)node * 128 + ch * 4) = make_float4(0.f, 0.f, 0.f, 0.f);
        }
        uint2 pk; pk.x = pack2bf_t(f.x, f.y); pk.y = pack2bf_t(f.z, f.w);
        *(uint2*)(s_nin + e * NIN_STR + 128 + ch * 4) = pk;
    }
    if (tid < 64) {
        int n = nb + tid;
        if (n < Nn) {
            float c = (float)ecnt[n]; c = (c < 1.0f) ? 1.0f : c;
            float inv = __fdividef(1.0f, c);
            cbuf[n * 3 + 0] += agg_coord[n * 3 + 0] * inv;
            cbuf[n * 3 + 1] += agg_coord[n * 3 + 1] * inv;
            cbuf[n * 3 + 2] += agg_coord[n * 3 + 2] * inv;
            agg_coord[n * 3 + 0] = 0.f; agg_coord[n * 3 + 1] = 0.f; agg_coord[n * 3 + 2] = 0.f;
        }
    }
    __syncthreads();

    const int lane = tid & 63, wave = tid >> 6;
    const int m = lane & 15, quad = lane >> 4;
    const int ws2 = wave >> 2, wt = wave & 3;
    const int rbase = ws2 * 32;

    // GEMM1^T: K=256
    {
        f4v acc[2][2];
        #pragma unroll
        for (int ct = 0; ct < 2; ct++) {
            float4 bb = *(const float4*)(b1 + (wt * 2 + ct) * 16 + quad * 4);
            acc[0][ct] = (f4v){bb.x, bb.y, bb.z, bb.w};
            acc[1][ct] = acc[0][ct];
        }
        const ushort* aBase = w1s + wt * 1024 + (size_t)lane * 8;
        #pragma unroll
        for (int kc = 0; kc < 8; kc++) {
            s8v a0 = *(const s8v*)(aBase + kc * 4096);
            s8v a1 = *(const s8v*)(aBase + kc * 4096 + 512);
            #pragma unroll
            for (int nt = 0; nt < 2; nt++) {
                s8v bf = *(const s8v*)(s_nin + (rbase + nt * 16 + m) * NIN_STR + kc * 32 + quad * 8);
                acc[nt][0] = __builtin_amdgcn_mfma_f32_16x16x32_bf16(a0, bf, acc[nt][0], 0, 0, 0);
                acc[nt][1] = __builtin_amdgcn_mfma_f32_16x16x32_bf16(a1, bf, acc[nt][1], 0, 0, 0);
            }
        }
        #pragma unroll
        for (int nt = 0; nt < 2; nt++) {
            int row = rbase + nt * 16 + m;
            #pragma unroll
            for (int ct = 0; ct < 2; ct++) {
                int colb = (wt * 2 + ct) * 16 + quad * 4;
                float v0 = silu_f(acc[nt][ct][0]);
                float v1 = silu_f(acc[nt][ct][1]);
                float v2 = silu_f(acc[nt][ct][2]);
                float v3 = silu_f(acc[nt][ct][3]);
                uint2 pk; pk.x = pack2bf_t(v0, v1); pk.y = pack2bf_t(v2, v3);
                *(uint2*)(s_t1 + row * EF_STR + colb) = pk;
            }
        }
    }
    __syncthreads();

    // GEMM2^T: K=128, residual epilogue
    {
        f4v acc[2][2];
        #pragma unroll
        for (int ct = 0; ct < 2; ct++) {
            float4 bb = *(const float4*)(b2 + (wt * 2 + ct) * 16 + quad * 4);
            acc[0][ct] = (f4v){bb.x, bb.y, bb.z, bb.w};
            acc[1][ct] = acc[0][ct];
        }
        const ushort* aBase = w2s + wt * 1024 + (size_t)lane * 8;
        #pragma unroll
        for (int kc = 0; kc < 4; kc++) {
            s8v a0 = *(const s8v*)(aBase + kc * 4096);
            s8v a1 = *(const s8v*)(aBase + kc * 4096 + 512);
            #pragma unroll
            for (int nt = 0; nt < 2; nt++) {
                s8v bf = *(const s8v*)(s_t1 + (rbase + nt * 16 + m) * EF_STR + kc * 32 + quad * 8);
                acc[nt][0] = __builtin_amdgcn_mfma_f32_16x16x32_bf16(a0, bf, acc[nt][0], 0, 0, 0);
                acc[nt][1] = __builtin_amdgcn_mfma_f32_16x16x32_bf16(a1, bf, acc[nt][1], 0, 0, 0);
            }
        }
        #pragma unroll
        for (int nt = 0; nt < 2; nt++) {
            int node = nb + rbase + nt * 16 + m;
            if (node < Nn) {
                #pragma unroll
                for (int ct = 0; ct < 2; ct++) {
                    int colb = (wt * 2 + ct) * 16 + quad * 4;
                    float4 old = *(const float4*)(hbuf + (size_t)node * 128 + colb);
                    float v0 = old.x + acc[nt][ct][0];
                    float v1 = old.y + acc[nt][ct][1];
                    float v2 = old.z + acc[nt][ct][2];
                    float v3 = old.w + acc[nt][ct][3];
                    *(float4*)(hbuf + (size_t)node * 128 + colb) = make_float4(v0, v1, v2, v3);
                    uint2 pk; pk.x = pack2bf_r(v0, v1); pk.y = pack2bf_r(v2, v3);
                    *(uint2*)(hbf + (size_t)node * 128 + colb) = pk;
                }
            }
        }
    }
}

// ---------------- output embedding (transposed MFMA) + coords out ----------------
__global__ void __launch_bounds__(512, 2) k_emb_out(
    const ushort* __restrict__ hbf, const float* __restrict__ cbuf,
    const ushort* __restrict__ ws_, const float* __restrict__ b, float* __restrict__ out)
{
    __shared__ alignas(16) ushort s_h[64 * EF_STR];
    const int tid = threadIdx.x;
    const int nb = blockIdx.x * 64;
    #pragma unroll
    for (int i = 0; i < 2; i++) {
        int idx = i * 512 + tid;
        int e = idx >> 4, ch = idx & 15;
        int node = nb + e;
        uint4 v = make_uint4(0, 0, 0, 0);
        if (node < Nn) v = *(const uint4*)(hbf + (size_t)node * 128 + ch * 8);
        *(uint4*)(s_h + e * EF_STR + ch * 8) = v;
    }
    if (tid < 192) {
        int n = nb + tid / 3, d = tid % 3;
        if (n < Nn) out[(size_t)Nn * 128 + n * 3 + d] = cbuf[n * 3 + d];
    }
    __syncthreads();
    const int lane = tid & 63, wave = tid >> 6;
    const int m = lane & 15, quad = lane >> 4;
    const int ws2 = wave >> 2, wt = wave & 3;
    const int rbase = ws2 * 32;
    f4v acc[2][2];
    #pragma unroll
    for (int ct = 0; ct < 2; ct++) {
        float4 bb = *(const float4*)(b + (wt * 2 + ct) * 16 + quad * 4);
        acc[0][ct] = (f4v){bb.x, bb.y, bb.z, bb.w};
        acc[1][ct] = acc[0][ct];
    }
    const ushort* aBase = ws_ + wt * 1024 + (size_t)lane * 8;
    #pragma unroll
    for (int kc = 0; kc < 4; kc++) {
        s8v a0 = *(const s8v*)(aBase + kc * 4096);
        s8v a1 = *(const s8v*)(aBase + kc * 4096 + 512);
        #pragma unroll
        for (int nt = 0; nt < 2; nt++) {
            s8v bf = *(const s8v*)(s_h + (rbase + nt * 16 + m) * EF_STR + kc * 32 + quad * 8);
            acc[nt][0] = __builtin_amdgcn_mfma_f32_16x16x32_bf16(a0, bf, acc[nt][0], 0, 0, 0);
            acc[nt][1] = __builtin_amdgcn_mfma_f32_16x16x32_bf16(a1, bf, acc[nt][1], 0, 0, 0);
        }
    }
    #pragma unroll
    for (int nt = 0; nt < 2; nt++) {
        int node = nb + rbase + nt * 16 + m;
        if (node < Nn) {
            #pragma unroll
            for (int ct = 0; ct < 2; ct++) {
                int colb = (wt * 2 + ct) * 16 + quad * 4;
                float4 o = make_float4(acc[nt][ct][0], acc[nt][ct][1],
                                       acc[nt][ct][2], acc[nt][ct][3]);
                *(float4*)(out + (size_t)node * 128 + colb) = o;
            }
        }
    }
}

// ---------------- host launcher ----------------
extern "C" void kernel_launch(void* const* d_in, const int* in_sizes, int n_in,
                              void* d_out, int out_size, void* d_ws, size_t ws_size,
                              hipStream_t stream)
{
    const float* h_in      = (const float*)d_in[0];
    const float* coords    = (const float*)d_in[1];
    const float* edge_attr = (const float*)d_in[2];
    const float* emb_in_W  = (const float*)d_in[3];
    const float* emb_in_b  = (const float*)d_in[4];
    const float* emb_out_W = (const float*)d_in[5];
    const float* emb_out_b = (const float*)d_in[6];
    const float* eW1 = (const float*)d_in[7];
    const float* eb1 = (const float*)d_in[8];
    const float* eW2 = (const float*)d_in[9];
    const float* eb2 = (const float*)d_in[10];
    const float* cW1 = (const float*)d_in[11];
    const float* cb1 = (const float*)d_in[12];
    const float* cWc = (const float*)d_in[13];
    const float* nW1 = (const float*)d_in[14];
    const float* nb1 = (const float*)d_in[15];
    const float* nW2 = (const float*)d_in[16];
    const float* nb2 = (const float*)d_in[17];
    const int*  eidx = (const int*)d_in[18];

    size_t off = 0;
    char* base = (char*)d_ws;
    auto alloc = [&](size_t bytes) -> char* {
        char* p = base + off;
        off += (bytes + 255) & ~(size_t)255;
        return p;
    };
    float*  hbuf      = (float*)alloc((size_t)Nn * 128 * 4);
    ushort* hbf       = (ushort*)alloc((size_t)Nn * 128 * 2);
    ushort* uvb       = (ushort*)alloc((size_t)Nn * 256 * 2);
    float*  cbuf      = (float*)alloc((size_t)Nn * 3 * 4);
    int*    ecnt      = (int*)alloc((size_t)Nn * 4);
    int*    cursor    = (int*)alloc((size_t)Nn * 4);
    int*    bsum      = (int*)alloc((size_t)NB_SCAN * 4);
    int*    srow      = (int*)alloc((size_t)Ee * 4);
    int*    scol      = (int*)alloc((size_t)Ee * 4);
    float*  sattr     = (float*)alloc((size_t)Ee * 4);
    float*  agg_feat  = (float*)alloc((size_t)Nn * 128 * 4);
    float*  agg_coord = (float*)alloc((size_t)Nn * 3 * 4);
    ushort* eW1tops   = (ushort*)alloc((size_t)4 * 16384 * 2);
    ushort* eW1mids   = (ushort*)alloc((size_t)4 * 16384 * 2);
    ushort* eW2s      = (ushort*)alloc((size_t)4 * 16384 * 2);
    ushort* cW1s      = (ushort*)alloc((size_t)4 * 16384 * 2);
    ushort* nW1s      = (ushort*)alloc((size_t)4 * 32768 * 2);
    ushort* nW2s      = (ushort*)alloc((size_t)4 * 16384 * 2);
    ushort* eInWs     = (ushort*)alloc((size_t)8192 * 2);
    ushort* eOutWs    = (ushort*)alloc((size_t)16384 * 2);

    k_swz_all<<<483328 / 256, 256, 0, stream>>>(
        eW1, eW2, cW1, nW1, nW2, emb_in_W, emb_out_W,
        eW1tops, eW1mids, eW2s, cW1s, nW1s, nW2s, eInWs, eOutWs);

    hipMemsetAsync(ecnt, 0, (size_t)Nn * 4, stream);
    k_count<<<Ee / 256, 256, 0, stream>>>(eidx, ecnt);
    k_bsum<<<NB_SCAN, 256, 0, stream>>>(ecnt, bsum);
    k_bscan<<<1, 256, 0, stream>>>(bsum);
    k_cursor<<<NB_SCAN, 256, 0, stream>>>(ecnt, bsum, cursor);
    k_scatter<<<Ee / 256, 256, 0, stream>>>(eidx, edge_attr, cursor, srow, scol, sattr);
    k_emb<<<(Nn + 63) / 64, 512, 0, stream>>>(h_in, coords, eInWs, emb_in_b, hbuf, hbf, cbuf);

    hipMemsetAsync(agg_feat, 0, (size_t)Nn * 128 * 4, stream);
    hipMemsetAsync(agg_coord, 0, (size_t)Nn * 3 * 4, stream);

    for (int l = 0; l < 4; l++) {
        k_uv<<<(Nn + 63) / 64, 512, 0, stream>>>(
            hbf, eW1tops + (size_t)l * 16384, eW1mids + (size_t)l * 16384,
            eb1 + l * 128, uvb);
        k_edge<<<Ee / 64, 512, 0, stream>>>(
            cbuf, srow, scol, sattr, uvb,
            eW1 + ((size_t)l * 258 + 256) * 128,   // Wd = W1 row 256
            eW1 + ((size_t)l * 258 + 257) * 128,   // Wa = W1 row 257
            eW2s + (size_t)l * 16384, eb2 + l * 128,
            cW1s + (size_t)l * 16384, cb1 + l * 128,
            cWc + l * 128,
            agg_feat, agg_coord);
        k_node<<<(Nn + 63) / 64, 512, 0, stream>>>(
            hbuf, hbf, cbuf, agg_feat, agg_coord, ecnt,
            nW1s + (size_t)l * 32768, nb1 + l * 128,
            nW2s + (size_t)l * 16384, nb2 + l * 128);
    }
    k_emb_out<<<(Nn + 63) / 64, 512, 0, stream>>>(hbf, cbuf, eOutWs, emb_out_b, (float*)d_out);
}